// Round 8
// baseline (524.760 us; speedup 1.0000x reference)
//
#include <hip/hip_runtime.h>
#include <math.h>

#define SEQ    100
#define BATCH  2048
#define DIM    128
#define NF     51
#define NLAYER 2
#define MTOT   (BATCH * NF)
#define BD     (BATCH * DIM)
#define XSTR   16384   // ushorts per batch in Xg: [c(128)][plane(2)][k(64)]
#define NBQ    96      // k_quant grid (all co-resident)

typedef __attribute__((ext_vector_type(8))) short bf16x8;
typedef __attribute__((ext_vector_type(4))) float f32x4v;

__device__ __forceinline__ unsigned cvtpk(float lo, float hi) {
    unsigned r;
    asm("v_cvt_pk_bf16_f32 %0, %1, %2" : "=v"(r) : "v"(lo), "v"(hi));
    return r;
}
__device__ __forceinline__ unsigned short f2bf(float f) {
    unsigned u = __float_as_uint(f);
    return (unsigned short)((u + 0x7FFFu + ((u >> 16) & 1u)) >> 16);
}
__device__ __forceinline__ float bf2f(unsigned short u) {
    return __uint_as_float((unsigned)u << 16);
}

// ---------------------------------------------------------------- tables ---
// imgF [p][k(64)][n(128)] bf16: p0 = 0.1*cos(2pi k n/100), p1 = -0.1*sin; 0-pad.
// imgI [p][n(128)][k(64)] bf16: p0 = a_k*cos, p1 = -a_k*sin; a_k = 0.1/0.2.
__global__ void k_tables(unsigned short* __restrict__ imgF,
                         unsigned short* __restrict__ imgI) {
    const int i = blockIdx.x * 256 + threadIdx.x;   // 16384 per table
    const float W = 6.28318530717958647692f / 100.f;
    if (i < 2 * 64 * 128) {
        const int p = i >> 13, k = (i >> 7) & 63, n = i & 127;
        float v = 0.f;
        if (k < NF && n < SEQ) {
            float s, c; sincosf((float)((k * n) % 100) * W, &s, &c);
            v = 0.1f * (p ? -s : c);
        }
        imgF[i] = f2bf(v);
    }
    if (i < 2 * 128 * 64) {
        const int p = i >> 13, n = (i >> 6) & 127, k = i & 63;
        float v = 0.f;
        if (k < NF && n < SEQ) {
            float s, c; sincosf((float)((k * n) % 100) * W, &s, &c);
            const float a = (k == 0 || k == 50) ? 0.1f : 0.2f;
            v = p ? -a * s : a * c;
        }
        imgI[i] = f2bf(v);
    }
}

// ------------------- A: LN + fwd DFT + X store (bf16) + energy + normE -----
// LDS = hT only (32768 B exactly -> 5 blocks/CU). epart/energy/median are
// unioned into hT after fragment reads (hT is dead then; extra barrier).
__global__ __launch_bounds__(256, 5) void k_fwd(
    const float* __restrict__ x,
    const float* __restrict__ gamma, const float* __restrict__ beta,
    const unsigned short* __restrict__ imgF,
    unsigned short* __restrict__ Xg,   // [BATCH][c][plane][k64] bf16
    float* __restrict__ normE)
{
    __shared__ __align__(16) unsigned short hT[128 * 128];   // 32 KB exactly

    const int b = blockIdx.x, t = threadIdx.x;
    const int lane = t & 63, wv = t >> 6, g4 = lane >> 4, cc = lane & 15;

    // ---- fused LN + h^T staging (single x fetch; loads hoisted) ----
    {
        const int c0 = lane * 2;
        const float2 gv = *(const float2*)&gamma[c0];
        const float2 bv = *(const float2*)&beta[c0];
        float2 v[4][8];
        #pragma unroll
        for (int slot = 0; slot < 4; ++slot) {
            const int n0 = (slot * 4 + wv) * 8;
            #pragma unroll
            for (int j = 0; j < 8; ++j)
                if (n0 + j < SEQ)
                    v[slot][j] = *(const float2*)&x[(size_t)(n0 + j) * BD + (size_t)b * DIM + c0];
        }
        #pragma unroll
        for (int slot = 0; slot < 4; ++slot) {
            const int chunk = slot * 4 + wv;       // 0..15
            const int n0 = chunk * 8;
            float he[8], ho[8];
            #pragma unroll
            for (int j = 0; j < 8; ++j) {
                he[j] = 0.f; ho[j] = 0.f;
                if (n0 + j < SEQ) {
                    float s  = v[slot][j].x + v[slot][j].y;
                    float s2 = fmaf(v[slot][j].x, v[slot][j].x, v[slot][j].y * v[slot][j].y);
                    #pragma unroll
                    for (int off = 1; off < 64; off <<= 1) {
                        s  += __shfl_xor(s,  off, 64);
                        s2 += __shfl_xor(s2, off, 64);
                    }
                    const float mu   = s * (1.f / 128.f);
                    const float rstd = rsqrtf(s2 * (1.f / 128.f) - mu * mu + 1e-5f);
                    he[j] = fmaf((v[slot][j].x - mu) * rstd, gv.x, bv.x);
                    ho[j] = fmaf((v[slot][j].y - mu) * rstd, gv.y, bv.y);
                }
            }
            int4 ve, vo;
            ve.x = (int)cvtpk(he[0], he[1]); ve.y = (int)cvtpk(he[2], he[3]);
            ve.z = (int)cvtpk(he[4], he[5]); ve.w = (int)cvtpk(he[6], he[7]);
            vo.x = (int)cvtpk(ho[0], ho[1]); vo.y = (int)cvtpk(ho[2], ho[3]);
            vo.z = (int)cvtpk(ho[4], ho[5]); vo.w = (int)cvtpk(ho[6], ho[7]);
            const int sw = (chunk ^ (lane & 7)) << 3;   // swizzle f(c)=(c>>1)&7
            *(int4*)&hT[(c0    ) * 128 + sw] = ve;
            *(int4*)&hT[(c0 + 1) * 128 + sw] = vo;
        }
    }
    __syncthreads();

    // B-fragments: wave's 2 c-tiles
    bf16x8 Bf[2][4];
    #pragma unroll
    for (int ct = 0; ct < 2; ++ct) {
        const int c = wv * 32 + ct * 16 + cc;
        #pragma unroll
        for (int ks = 0; ks < 4; ++ks)
            Bf[ct][ks] = *(const bf16x8*)&hT[c * 128 + (((ks * 4 + g4) ^ (cc >> 1)) << 3)];
    }
    __syncthreads();   // all hT reads complete -> reuse hT as f32 scratch

    float* epart    = (float*)hT;          // [64][4]
    float* energy_s = (float*)hT + 256;    // [64]
    float* medp     = (float*)hT + 320;    // [1]

    #pragma unroll
    for (int mt = 0; mt < 4; ++mt) {
        const int kr = mt * 16 + cc;
        f32x4v aR[2], aI[2];
        aR[0] = aR[1] = aI[0] = aI[1] = (f32x4v){0.f, 0.f, 0.f, 0.f};
        #pragma unroll
        for (int ks = 0; ks < 4; ++ks) {
            const int e0 = kr * 128 + ks * 32 + g4 * 8;
            const bf16x8 A0 = *(const bf16x8*)&imgF[e0];
            const bf16x8 A1 = *(const bf16x8*)&imgF[8192 + e0];
            #pragma unroll
            for (int ct = 0; ct < 2; ++ct) {
                aR[ct] = __builtin_amdgcn_mfma_f32_16x16x32_bf16(A0, Bf[ct][ks], aR[ct], 0, 0, 0);
                aI[ct] = __builtin_amdgcn_mfma_f32_16x16x32_bf16(A1, Bf[ct][ks], aI[ct], 0, 0, 0);
            }
        }
        // energy partials (f32, before bf16 rounding)
        #pragma unroll
        for (int reg = 0; reg < 4; ++reg) {
            float e = aR[0][reg] * aR[0][reg] + aI[0][reg] * aI[0][reg]
                    + aR[1][reg] * aR[1][reg] + aI[1][reg] * aI[1][reg];
            e += __shfl_xor(e, 1, 64); e += __shfl_xor(e, 2, 64);
            e += __shfl_xor(e, 4, 64); e += __shfl_xor(e, 8, 64);
            if (cc == 0) epart[(mt * 16 + g4 * 4 + reg) * 4 + wv] = e;
        }
        // X store: acc (k=mt*16+g4*4+reg, c) -> Xg[b][c][plane][k] packed bf16
        #pragma unroll
        for (int ct = 0; ct < 2; ++ct) {
            const int c = wv * 32 + ct * 16 + cc;
            unsigned short* Xb = Xg + (size_t)b * XSTR + (size_t)c * 128;
            const int k0 = mt * 16 + g4 * 4;
            uint2 pr, pi;
            pr.x = cvtpk(aR[ct][0], aR[ct][1]); pr.y = cvtpk(aR[ct][2], aR[ct][3]);
            pi.x = cvtpk(aI[ct][0], aI[ct][1]); pi.y = cvtpk(aI[ct][2], aI[ct][3]);
            *(uint2*)&Xb[k0]      = pr;   // plane 0 (Re)
            *(uint2*)&Xb[64 + k0] = pi;   // plane 1 (Im)
        }
    }
    __syncthreads();
    if (t < 64) energy_s[t] = epart[4 * t] + epart[4 * t + 1]
                            + epart[4 * t + 2] + epart[4 * t + 3];
    __syncthreads();
    if (t < NF) {
        const float e = energy_s[t];
        int cnt = 0;
        for (int j = 0; j < NF; ++j) {
            const float ej = energy_s[j];
            cnt += (ej < e || (ej == e && j < t)) ? 1 : 0;
        }
        if (cnt == (NF - 1) / 2) *medp = e;
    }
    __syncthreads();
    if (t < NF) normE[b * NF + t] = energy_s[t] / (*medp + 1e-6f);
}

// ------------------------- fused 3-round radix select (single kernel) ------
// hist layout (u32): [0,2048) round0 | [2048,6144) round1 (2 ranks) |
//                    [6144,8192) round2 (2 ranks). counter = 1 u32.
__device__ __forceinline__ void gbar(unsigned* counter, unsigned target) {
    __syncthreads();
    __threadfence();
    if (threadIdx.x == 0) {
        __hip_atomic_fetch_add(counter, 1u, __ATOMIC_ACQ_REL, __HIP_MEMORY_SCOPE_AGENT);
        while (__hip_atomic_load(counter, __ATOMIC_ACQUIRE, __HIP_MEMORY_SCOPE_AGENT) < target)
            __builtin_amdgcn_s_sleep(8);
    }
    __syncthreads();
}

// scan one 2-rank histogram round; t<128 participate; updates sp/sc in LDS.
// shared_region: round0 (both ranks read same 2048-bin hist, no entry prefix).
__device__ __forceinline__ void scan2(const unsigned* __restrict__ H0,
                                      int bins, int shift, bool entry,
                                      unsigned r0, unsigned* sp, unsigned* sc)
{
    const int t = threadIdx.x;
    if (t < 128) {
        const int j = t >> 6, ln = t & 63;
        const unsigned rk = r0 + (unsigned)j;
        const unsigned oldsp = entry ? sp[j] : 0u;
        const unsigned oldsc = entry ? sc[j] : 0u;
        const unsigned rem = rk - oldsc;
        const unsigned* H = H0 + (entry ? j * bins : 0);
        const int per = bins / 64;
        unsigned sum = 0;
        for (int i = 0; i < per; ++i)
            sum += __hip_atomic_load(&H[ln * per + i], __ATOMIC_RELAXED, __HIP_MEMORY_SCOPE_AGENT);
        unsigned pre = sum;
        #pragma unroll
        for (int off = 1; off < 64; off <<= 1) {
            const unsigned tt = __shfl_up(pre, off, 64);
            if (ln >= off) pre += tt;
        }
        const unsigned excl = pre - sum;
        if (rem >= excl && rem < excl + sum) {
            unsigned cum = excl;
            for (int i = 0; i < per; ++i) {
                const unsigned hc = __hip_atomic_load(&H[ln * per + i],
                                        __ATOMIC_RELAXED, __HIP_MEMORY_SCOPE_AGENT);
                if (rem < cum + hc) {
                    sp[j] = oldsp | ((unsigned)(ln * per + i) << shift);
                    sc[j] = oldsc + cum;
                    break;
                }
                cum += hc;
            }
        }
    }
    __syncthreads();
}

__global__ void k_quant(const float* __restrict__ normE,
                        unsigned* __restrict__ hist,
                        unsigned* __restrict__ counter,
                        const float* __restrict__ thrp,
                        const int layer,
                        float* __restrict__ thresh)
{
    __shared__ unsigned lh[4096];
    __shared__ unsigned sp[2], sc[2];
    const int t = threadIdx.x, bid = blockIdx.x;
    const float q = thrp[layer] * (float)(MTOT - 1);
    const unsigned r0 = (unsigned)floorf(q);

    // stage 0: zero hist
    for (int i = bid * 256 + t; i < 8192; i += NBQ * 256) hist[i] = 0u;
    gbar(counter, NBQ * 1);

    // round 0 accumulate (11 high bits)
    for (int i = t; i < 2048; i += 256) lh[i] = 0;
    __syncthreads();
    for (int i = bid * 256 + t; i < MTOT; i += NBQ * 256)
        atomicAdd(&lh[__float_as_uint(normE[i]) >> 21], 1u);
    __syncthreads();
    for (int i = t; i < 2048; i += 256) {
        const unsigned c = lh[i];
        if (c) atomicAdd(&hist[i], c);
    }
    gbar(counter, NBQ * 2);

    // round 0 scan (redundant per block) -> sp/sc; round 1 accumulate
    scan2(hist, 2048, 21, false, r0, sp, sc);
    {
        const unsigned p0 = sp[0], p1 = sp[1];
        for (int i = t; i < 4096; i += 256) lh[i] = 0;
        __syncthreads();
        for (int i = bid * 256 + t; i < MTOT; i += NBQ * 256) {
            const unsigned v = __float_as_uint(normE[i]);
            const unsigned bin = (v >> 10) & 2047u;
            if ((v & 0xFFE00000u) == p0) atomicAdd(&lh[bin], 1u);
            if ((v & 0xFFE00000u) == p1) atomicAdd(&lh[2048 + bin], 1u);
        }
        __syncthreads();
        for (int i = t; i < 4096; i += 256) {
            const unsigned c = lh[i];
            if (c) atomicAdd(&hist[2048 + i], c);
        }
    }
    gbar(counter, NBQ * 3);

    // round 1 scan -> sp/sc; round 2 accumulate (10 low bits)
    scan2(hist + 2048, 2048, 10, true, r0, sp, sc);
    {
        const unsigned p0 = sp[0], p1 = sp[1];
        for (int i = t; i < 2048; i += 256) lh[i] = 0;
        __syncthreads();
        for (int i = bid * 256 + t; i < MTOT; i += NBQ * 256) {
            const unsigned v = __float_as_uint(normE[i]);
            const unsigned bin = v & 1023u;
            if ((v & 0xFFFFFC00u) == p0) atomicAdd(&lh[bin], 1u);
            if ((v & 0xFFFFFC00u) == p1) atomicAdd(&lh[1024 + bin], 1u);
        }
        __syncthreads();
        for (int i = t; i < 2048; i += 256) {
            const unsigned c = lh[i];
            if (c) atomicAdd(&hist[6144 + i], c);
        }
    }
    gbar(counter, NBQ * 4);

    // block 0: final scan + threshold + counter reset
    if (bid == 0) {
        scan2(hist + 6144, 1024, 0, true, r0, sp, sc);
        if (t == 0) {
            const float v0 = __uint_as_float(sp[0]);
            const float v1 = __uint_as_float(sp[1]);
            const float frac = q - floorf(q);
            thresh[0] = v0 * (1.f - frac) + v1 * frac;
            __threadfence();
            __hip_atomic_store(counter, 0u, __ATOMIC_RELEASE, __HIP_MEMORY_SCOPE_AGENT);
        }
    }
}

// --------------- C: load X + mask/weight + inv DFT + residual (no LDS) -----
__global__ __launch_bounds__(256, 8) void k_asb(
    const float* __restrict__ x,
    const float* __restrict__ cw, const float* __restrict__ cwh,
    const unsigned short* __restrict__ Xg,
    const unsigned short* __restrict__ imgI,
    const float* __restrict__ normE, const float* __restrict__ thresh,
    float* __restrict__ out)
{
    __shared__ __align__(16) float mask_s[64];

    const int b = blockIdx.x, t = threadIdx.x;
    const int lane = t & 63, wv = t >> 6, g4 = lane >> 4, cc = lane & 15;

    if (t < 64) mask_s[t] = (t < NF && normE[b * NF + t] < thresh[0]) ? 1.f : 0.f;
    __syncthreads();   // the only barrier

    // load X fragments, apply (w + mask*wh) in f32, repack as bf16 B-frags
    bf16x8 Yr[2][2], Yi[2][2];
    #pragma unroll
    for (int ct = 0; ct < 2; ++ct) {
        const int c = wv * 32 + ct * 16 + cc;
        const unsigned short* Xb = Xg + (size_t)b * XSTR + (size_t)c * 128;
        const float2 w2 = *(const float2*)&cw[2 * c];
        const float2 h2 = *(const float2*)&cwh[2 * c];
        #pragma unroll
        for (int kb = 0; kb < 2; ++kb) {
            const bf16x8 xr = *(const bf16x8*)&Xb[kb * 32 + g4 * 8];
            const bf16x8 xi = *(const bf16x8*)&Xb[64 + kb * 32 + g4 * 8];
            float yr[8], yi[8];
            #pragma unroll
            for (int j = 0; j < 8; ++j) {
                const float m   = mask_s[kb * 32 + g4 * 8 + j];
                const float fre = fmaf(m, h2.x, w2.x);
                const float fim = fmaf(m, h2.y, w2.y);
                const float fxr = bf2f((unsigned short)xr[j]);
                const float fxi = bf2f((unsigned short)xi[j]);
                yr[j] = fxr * fre - fxi * fim;
                yi[j] = fxr * fim + fxi * fre;
            }
            unsigned ur[4], ui[4];
            #pragma unroll
            for (int jj = 0; jj < 4; ++jj) {
                ur[jj] = cvtpk(yr[2 * jj], yr[2 * jj + 1]);
                ui[jj] = cvtpk(yi[2 * jj], yi[2 * jj + 1]);
            }
            Yr[ct][kb] = *(bf16x8*)ur;
            Yi[ct][kb] = *(bf16x8*)ui;
        }
    }

    // inverse DFT + residual + store
    #pragma unroll
    for (int mt = 0; mt < 7; ++mt) {
        const int nr = mt * 16 + cc;
        f32x4v o[2];
        o[0] = o[1] = (f32x4v){0.f, 0.f, 0.f, 0.f};
        #pragma unroll
        for (int kb = 0; kb < 2; ++kb) {
            const int e0 = nr * 64 + kb * 32 + g4 * 8;
            const bf16x8 A0 = *(const bf16x8*)&imgI[e0];
            const bf16x8 A1 = *(const bf16x8*)&imgI[8192 + e0];
            #pragma unroll
            for (int ct = 0; ct < 2; ++ct) {
                o[ct] = __builtin_amdgcn_mfma_f32_16x16x32_bf16(A0, Yr[ct][kb], o[ct], 0, 0, 0);
                o[ct] = __builtin_amdgcn_mfma_f32_16x16x32_bf16(A1, Yi[ct][kb], o[ct], 0, 0, 0);
            }
        }
        #pragma unroll
        for (int ct = 0; ct < 2; ++ct) {
            const int c = wv * 32 + ct * 16 + cc;
            #pragma unroll
            for (int reg = 0; reg < 4; ++reg) {
                const int n = mt * 16 + g4 * 4 + reg;
                if (n < SEQ) {
                    const size_t idx = (size_t)n * BD + (size_t)b * DIM + c;
                    out[idx] = x[idx] + o[ct][reg];
                }
            }
        }
    }
}

// ---------------------------------------------------------------------------
extern "C" void kernel_launch(void* const* d_in, const int* in_sizes, int n_in,
                              void* d_out, int out_size, void* d_ws, size_t ws_size,
                              hipStream_t stream)
{
    (void)in_sizes; (void)n_in; (void)out_size; (void)ws_size;
    const float* x    = (const float*)d_in[0];
    const float* cw   = (const float*)d_in[1];
    const float* cwh  = (const float*)d_in[2];
    const float* thrp = (const float*)d_in[3];
    const float* gam  = (const float*)d_in[4];
    const float* bet  = (const float*)d_in[5];
    float* out = (float*)d_out;

    char* ws = (char*)d_ws;
    unsigned short* imgF = (unsigned short*)(ws);                    // 32768 B
    unsigned short* imgI = (unsigned short*)(ws + 32768);            // 32768 B
    unsigned short* Xg   = (unsigned short*)(ws + 65536);            // 67,108,864 B
    float* normE      = (float*)(ws + 65536 + 67108864);             // 417,792 B
    unsigned* hist    = (unsigned*)(ws + 65536 + 67108864 + 417792); // 32768 B
    unsigned* counter = (unsigned*)(ws + 65536 + 67108864 + 417792 + 32768);  // 64 B
    float* thresh     = (float*)(ws + 65536 + 67108864 + 417792 + 32768 + 64);

    k_tables<<<64, 256, 0, stream>>>(imgF, imgI);
    hipMemsetAsync(counter, 0, 64, stream);   // counter must be 0 (ws poisoned 0xAA)

    for (int l = 0; l < NLAYER; ++l) {
        const float* xi = (l == 0) ? x : out;
        k_fwd<<<BATCH, 256, 0, stream>>>(xi, gam + l * DIM, bet + l * DIM,
                                         imgF, Xg, normE);
        k_quant<<<NBQ, 256, 0, stream>>>(normE, hist, counter, thrp, l, thresh);
        k_asb<<<BATCH, 256, 0, stream>>>(xi, cw + l * DIM * 2, cwh + l * DIM * 2,
                                         Xg, imgI, normE, thresh, out);
    }
}

// Round 9
// 458.125 us; speedup vs baseline: 1.1455x; 1.1455x over previous
//
#include <hip/hip_runtime.h>
#include <math.h>

#define SEQ    100
#define BATCH  2048
#define DIM    128
#define NF     51
#define NLAYER 2
#define MTOT   (BATCH * NF)
#define BD     (BATCH * DIM)
#define XSTR   16384   // ushorts per batch in Xg: [c(128)][plane(2)][k(64)]
#define NBQ    96      // k_quant grid (all co-resident)

typedef __attribute__((ext_vector_type(8))) short bf16x8;
typedef __attribute__((ext_vector_type(4))) float f32x4v;

__device__ __forceinline__ unsigned cvtpk(float lo, float hi) {
    unsigned r;
    asm("v_cvt_pk_bf16_f32 %0, %1, %2" : "=v"(r) : "v"(lo), "v"(hi));
    return r;
}
__device__ __forceinline__ unsigned short f2bf(float f) {
    unsigned u = __float_as_uint(f);
    return (unsigned short)((u + 0x7FFFu + ((u >> 16) & 1u)) >> 16);
}
__device__ __forceinline__ float bf2f(unsigned short u) {
    return __uint_as_float((unsigned)u << 16);
}

// ---------------------------------------------------------------- tables ---
// imgF [p][k(64)][n(128)] bf16: p0 = 0.1*cos(2pi k n/100), p1 = -0.1*sin; 0-pad.
// imgI [p][n(128)][k(64)] bf16: p0 = a_k*cos, p1 = -a_k*sin; a_k = 0.1/0.2.
__global__ void k_tables(unsigned short* __restrict__ imgF,
                         unsigned short* __restrict__ imgI) {
    const int i = blockIdx.x * 256 + threadIdx.x;   // 16384 per table
    const float W = 6.28318530717958647692f / 100.f;
    if (i < 2 * 64 * 128) {
        const int p = i >> 13, k = (i >> 7) & 63, n = i & 127;
        float v = 0.f;
        if (k < NF && n < SEQ) {
            float s, c; sincosf((float)((k * n) % 100) * W, &s, &c);
            v = 0.1f * (p ? -s : c);
        }
        imgF[i] = f2bf(v);
    }
    if (i < 2 * 128 * 64) {
        const int p = i >> 13, n = (i >> 6) & 127, k = i & 63;
        float v = 0.f;
        if (k < NF && n < SEQ) {
            float s, c; sincosf((float)((k * n) % 100) * W, &s, &c);
            const float a = (k == 0 || k == 50) ? 0.1f : 0.2f;
            v = p ? -a * s : a * c;
        }
        imgI[i] = f2bf(v);
    }
}

// ------------------- A: LN + fwd DFT + X store (bf16) + energy + normE -----
// LDS = hT only (32768 B exactly -> 5 blocks/CU). epart/energy/median are
// unioned into hT after fragment reads (hT dead then; extra barrier).
__global__ __launch_bounds__(256, 5) void k_fwd(
    const float* __restrict__ x,
    const float* __restrict__ gamma, const float* __restrict__ beta,
    const unsigned short* __restrict__ imgF,
    unsigned short* __restrict__ Xg,   // [BATCH][c][plane][k64] bf16
    float* __restrict__ normE)
{
    __shared__ __align__(16) unsigned short hT[128 * 128];   // 32 KB exactly

    const int b = blockIdx.x, t = threadIdx.x;
    const int lane = t & 63, wv = t >> 6, g4 = lane >> 4, cc = lane & 15;

    // ---- fused LN + h^T staging (single x fetch; loads hoisted) ----
    {
        const int c0 = lane * 2;
        const float2 gv = *(const float2*)&gamma[c0];
        const float2 bv = *(const float2*)&beta[c0];
        float2 v[4][8];
        #pragma unroll
        for (int slot = 0; slot < 4; ++slot) {
            const int n0 = (slot * 4 + wv) * 8;
            #pragma unroll
            for (int j = 0; j < 8; ++j)
                if (n0 + j < SEQ)
                    v[slot][j] = *(const float2*)&x[(size_t)(n0 + j) * BD + (size_t)b * DIM + c0];
        }
        #pragma unroll
        for (int slot = 0; slot < 4; ++slot) {
            const int chunk = slot * 4 + wv;       // 0..15
            const int n0 = chunk * 8;
            float he[8], ho[8];
            #pragma unroll
            for (int j = 0; j < 8; ++j) {
                he[j] = 0.f; ho[j] = 0.f;
                if (n0 + j < SEQ) {
                    float s  = v[slot][j].x + v[slot][j].y;
                    float s2 = fmaf(v[slot][j].x, v[slot][j].x, v[slot][j].y * v[slot][j].y);
                    #pragma unroll
                    for (int off = 1; off < 64; off <<= 1) {
                        s  += __shfl_xor(s,  off, 64);
                        s2 += __shfl_xor(s2, off, 64);
                    }
                    const float mu   = s * (1.f / 128.f);
                    const float rstd = rsqrtf(s2 * (1.f / 128.f) - mu * mu + 1e-5f);
                    he[j] = fmaf((v[slot][j].x - mu) * rstd, gv.x, bv.x);
                    ho[j] = fmaf((v[slot][j].y - mu) * rstd, gv.y, bv.y);
                }
            }
            int4 ve, vo;
            ve.x = (int)cvtpk(he[0], he[1]); ve.y = (int)cvtpk(he[2], he[3]);
            ve.z = (int)cvtpk(he[4], he[5]); ve.w = (int)cvtpk(he[6], he[7]);
            vo.x = (int)cvtpk(ho[0], ho[1]); vo.y = (int)cvtpk(ho[2], ho[3]);
            vo.z = (int)cvtpk(ho[4], ho[5]); vo.w = (int)cvtpk(ho[6], ho[7]);
            const int sw = (chunk ^ (lane & 7)) << 3;   // swizzle f(c)=(c>>1)&7
            *(int4*)&hT[(c0    ) * 128 + sw] = ve;
            *(int4*)&hT[(c0 + 1) * 128 + sw] = vo;
        }
    }
    __syncthreads();

    // B-fragments: wave's 2 c-tiles
    bf16x8 Bf[2][4];
    #pragma unroll
    for (int ct = 0; ct < 2; ++ct) {
        const int c = wv * 32 + ct * 16 + cc;
        #pragma unroll
        for (int ks = 0; ks < 4; ++ks)
            Bf[ct][ks] = *(const bf16x8*)&hT[c * 128 + (((ks * 4 + g4) ^ (cc >> 1)) << 3)];
    }
    __syncthreads();   // all hT reads complete -> reuse hT as f32 scratch

    float* epart    = (float*)hT;          // [64][4]
    float* energy_s = (float*)hT + 256;    // [64]
    float* medp     = (float*)hT + 320;    // [1]

    #pragma unroll
    for (int mt = 0; mt < 4; ++mt) {
        const int kr = mt * 16 + cc;
        f32x4v aR[2], aI[2];
        aR[0] = aR[1] = aI[0] = aI[1] = (f32x4v){0.f, 0.f, 0.f, 0.f};
        #pragma unroll
        for (int ks = 0; ks < 4; ++ks) {
            const int e0 = kr * 128 + ks * 32 + g4 * 8;
            const bf16x8 A0 = *(const bf16x8*)&imgF[e0];
            const bf16x8 A1 = *(const bf16x8*)&imgF[8192 + e0];
            #pragma unroll
            for (int ct = 0; ct < 2; ++ct) {
                aR[ct] = __builtin_amdgcn_mfma_f32_16x16x32_bf16(A0, Bf[ct][ks], aR[ct], 0, 0, 0);
                aI[ct] = __builtin_amdgcn_mfma_f32_16x16x32_bf16(A1, Bf[ct][ks], aI[ct], 0, 0, 0);
            }
        }
        // energy partials (f32, before bf16 rounding)
        #pragma unroll
        for (int reg = 0; reg < 4; ++reg) {
            float e = aR[0][reg] * aR[0][reg] + aI[0][reg] * aI[0][reg]
                    + aR[1][reg] * aR[1][reg] + aI[1][reg] * aI[1][reg];
            e += __shfl_xor(e, 1, 64); e += __shfl_xor(e, 2, 64);
            e += __shfl_xor(e, 4, 64); e += __shfl_xor(e, 8, 64);
            if (cc == 0) epart[(mt * 16 + g4 * 4 + reg) * 4 + wv] = e;
        }
        // X store: acc (k=mt*16+g4*4+reg, c) -> Xg[b][c][plane][k] packed bf16
        #pragma unroll
        for (int ct = 0; ct < 2; ++ct) {
            const int c = wv * 32 + ct * 16 + cc;
            unsigned short* Xb = Xg + (size_t)b * XSTR + (size_t)c * 128;
            const int k0 = mt * 16 + g4 * 4;
            uint2 pr, pi;
            pr.x = cvtpk(aR[ct][0], aR[ct][1]); pr.y = cvtpk(aR[ct][2], aR[ct][3]);
            pi.x = cvtpk(aI[ct][0], aI[ct][1]); pi.y = cvtpk(aI[ct][2], aI[ct][3]);
            *(uint2*)&Xb[k0]      = pr;   // plane 0 (Re)
            *(uint2*)&Xb[64 + k0] = pi;   // plane 1 (Im)
        }
    }
    __syncthreads();
    if (t < 64) energy_s[t] = epart[4 * t] + epart[4 * t + 1]
                            + epart[4 * t + 2] + epart[4 * t + 3];
    __syncthreads();
    if (t < NF) {
        const float e = energy_s[t];
        int cnt = 0;
        for (int j = 0; j < NF; ++j) {
            const float ej = energy_s[j];
            cnt += (ej < e || (ej == e && j < t)) ? 1 : 0;
        }
        if (cnt == (NF - 1) / 2) *medp = e;
    }
    __syncthreads();
    if (t < NF) normE[b * NF + t] = energy_s[t] / (*medp + 1e-6f);
}

// ------------------------- fused 3-round radix select (single kernel) ------
// hist layout (u32): [0,2048) round0 | [2048,6144) round1 (2 ranks) |
//                    [6144,8192) round2 (2 ranks).
// counters: ONE SLOT PER BARRIER PER LAYER (8 u32) — monotonic, zeroed by the
// captured memset each replay; no in-kernel reset, no reset race.
__device__ __forceinline__ void gbar(unsigned* slot) {
    __syncthreads();
    __threadfence();
    if (threadIdx.x == 0) {
        __hip_atomic_fetch_add(slot, 1u, __ATOMIC_ACQ_REL, __HIP_MEMORY_SCOPE_AGENT);
        while (__hip_atomic_load(slot, __ATOMIC_ACQUIRE, __HIP_MEMORY_SCOPE_AGENT) < NBQ)
            __builtin_amdgcn_s_sleep(8);
    }
    __syncthreads();
}

// scan one 2-rank histogram round; t<128 participate; updates sp/sc in LDS.
__device__ __forceinline__ void scan2(const unsigned* __restrict__ H0,
                                      int bins, int shift, bool entry,
                                      unsigned r0, unsigned* sp, unsigned* sc)
{
    const int t = threadIdx.x;
    if (t < 128) {
        const int j = t >> 6, ln = t & 63;
        const unsigned rk = r0 + (unsigned)j;
        const unsigned oldsp = entry ? sp[j] : 0u;
        const unsigned oldsc = entry ? sc[j] : 0u;
        const unsigned rem = rk - oldsc;
        const unsigned* H = H0 + (entry ? j * bins : 0);
        const int per = bins / 64;
        unsigned sum = 0;
        for (int i = 0; i < per; ++i)
            sum += __hip_atomic_load(&H[ln * per + i], __ATOMIC_RELAXED, __HIP_MEMORY_SCOPE_AGENT);
        unsigned pre = sum;
        #pragma unroll
        for (int off = 1; off < 64; off <<= 1) {
            const unsigned tt = __shfl_up(pre, off, 64);
            if (ln >= off) pre += tt;
        }
        const unsigned excl = pre - sum;
        if (rem >= excl && rem < excl + sum) {
            unsigned cum = excl;
            for (int i = 0; i < per; ++i) {
                const unsigned hc = __hip_atomic_load(&H[ln * per + i],
                                        __ATOMIC_RELAXED, __HIP_MEMORY_SCOPE_AGENT);
                if (rem < cum + hc) {
                    sp[j] = oldsp | ((unsigned)(ln * per + i) << shift);
                    sc[j] = oldsc + cum;
                    break;
                }
                cum += hc;
            }
        }
    }
    __syncthreads();
}

__global__ void k_quant(const float* __restrict__ normE,
                        unsigned* __restrict__ hist,
                        unsigned* __restrict__ counters,   // [NLAYER*4]
                        const float* __restrict__ thrp,
                        const int layer,
                        float* __restrict__ thresh)
{
    __shared__ unsigned lh[4096];
    __shared__ unsigned sp[2], sc[2];
    const int t = threadIdx.x, bid = blockIdx.x;
    const float q = thrp[layer] * (float)(MTOT - 1);
    const unsigned r0 = (unsigned)floorf(q);
    unsigned* cnt = counters + layer * 4;

    // stage 0: zero hist (hist is re-zeroed here each layer, each replay)
    for (int i = bid * 256 + t; i < 8192; i += NBQ * 256) hist[i] = 0u;
    gbar(cnt + 0);

    // round 0 accumulate (11 high bits)
    for (int i = t; i < 2048; i += 256) lh[i] = 0;
    __syncthreads();
    for (int i = bid * 256 + t; i < MTOT; i += NBQ * 256)
        atomicAdd(&lh[__float_as_uint(normE[i]) >> 21], 1u);
    __syncthreads();
    for (int i = t; i < 2048; i += 256) {
        const unsigned c = lh[i];
        if (c) atomicAdd(&hist[i], c);
    }
    gbar(cnt + 1);

    // round 0 scan (redundant per block) -> sp/sc; round 1 accumulate
    scan2(hist, 2048, 21, false, r0, sp, sc);
    {
        const unsigned p0 = sp[0], p1 = sp[1];
        for (int i = t; i < 4096; i += 256) lh[i] = 0;
        __syncthreads();
        for (int i = bid * 256 + t; i < MTOT; i += NBQ * 256) {
            const unsigned v = __float_as_uint(normE[i]);
            const unsigned bin = (v >> 10) & 2047u;
            if ((v & 0xFFE00000u) == p0) atomicAdd(&lh[bin], 1u);
            if ((v & 0xFFE00000u) == p1) atomicAdd(&lh[2048 + bin], 1u);
        }
        __syncthreads();
        for (int i = t; i < 4096; i += 256) {
            const unsigned c = lh[i];
            if (c) atomicAdd(&hist[2048 + i], c);
        }
    }
    gbar(cnt + 2);

    // round 1 scan -> sp/sc; round 2 accumulate (10 low bits)
    scan2(hist + 2048, 2048, 10, true, r0, sp, sc);
    {
        const unsigned p0 = sp[0], p1 = sp[1];
        for (int i = t; i < 2048; i += 256) lh[i] = 0;
        __syncthreads();
        for (int i = bid * 256 + t; i < MTOT; i += NBQ * 256) {
            const unsigned v = __float_as_uint(normE[i]);
            const unsigned bin = v & 1023u;
            if ((v & 0xFFFFFC00u) == p0) atomicAdd(&lh[bin], 1u);
            if ((v & 0xFFFFFC00u) == p1) atomicAdd(&lh[1024 + bin], 1u);
        }
        __syncthreads();
        for (int i = t; i < 2048; i += 256) {
            const unsigned c = lh[i];
            if (c) atomicAdd(&hist[6144 + i], c);
        }
    }
    gbar(cnt + 3);

    // block 0: final scan + threshold
    if (bid == 0) {
        scan2(hist + 6144, 1024, 0, true, r0, sp, sc);
        if (t == 0) {
            const float v0 = __uint_as_float(sp[0]);
            const float v1 = __uint_as_float(sp[1]);
            const float frac = q - floorf(q);
            thresh[0] = v0 * (1.f - frac) + v1 * frac;
        }
    }
}

// --------------- C: load X + mask/weight + inv DFT + residual (no LDS) -----
__global__ __launch_bounds__(256, 6) void k_asb(
    const float* __restrict__ x,
    const float* __restrict__ cw, const float* __restrict__ cwh,
    const unsigned short* __restrict__ Xg,
    const unsigned short* __restrict__ imgI,
    const float* __restrict__ normE, const float* __restrict__ thresh,
    float* __restrict__ out)
{
    __shared__ __align__(16) float mask_s[64];

    const int b = blockIdx.x, t = threadIdx.x;
    const int lane = t & 63, wv = t >> 6, g4 = lane >> 4, cc = lane & 15;

    if (t < 64) mask_s[t] = (t < NF && normE[b * NF + t] < thresh[0]) ? 1.f : 0.f;
    __syncthreads();   // the only barrier

    // load X fragments, apply (w + mask*wh) in f32, repack as bf16 B-frags
    bf16x8 Yr[2][2], Yi[2][2];
    #pragma unroll
    for (int ct = 0; ct < 2; ++ct) {
        const int c = wv * 32 + ct * 16 + cc;
        const unsigned short* Xb = Xg + (size_t)b * XSTR + (size_t)c * 128;
        const float2 w2 = *(const float2*)&cw[2 * c];
        const float2 h2 = *(const float2*)&cwh[2 * c];
        #pragma unroll
        for (int kb = 0; kb < 2; ++kb) {
            const bf16x8 xr = *(const bf16x8*)&Xb[kb * 32 + g4 * 8];
            const bf16x8 xi = *(const bf16x8*)&Xb[64 + kb * 32 + g4 * 8];
            float yr[8], yi[8];
            #pragma unroll
            for (int j = 0; j < 8; ++j) {
                const float m   = mask_s[kb * 32 + g4 * 8 + j];
                const float fre = fmaf(m, h2.x, w2.x);
                const float fim = fmaf(m, h2.y, w2.y);
                const float fxr = bf2f((unsigned short)xr[j]);
                const float fxi = bf2f((unsigned short)xi[j]);
                yr[j] = fxr * fre - fxi * fim;
                yi[j] = fxr * fim + fxi * fre;
            }
            unsigned ur[4], ui[4];
            #pragma unroll
            for (int jj = 0; jj < 4; ++jj) {
                ur[jj] = cvtpk(yr[2 * jj], yr[2 * jj + 1]);
                ui[jj] = cvtpk(yi[2 * jj], yi[2 * jj + 1]);
            }
            Yr[ct][kb] = *(bf16x8*)ur;
            Yi[ct][kb] = *(bf16x8*)ui;
        }
    }

    // inverse DFT + residual + store
    #pragma unroll
    for (int mt = 0; mt < 7; ++mt) {
        const int nr = mt * 16 + cc;
        f32x4v o[2];
        o[0] = o[1] = (f32x4v){0.f, 0.f, 0.f, 0.f};
        #pragma unroll
        for (int kb = 0; kb < 2; ++kb) {
            const int e0 = nr * 64 + kb * 32 + g4 * 8;
            const bf16x8 A0 = *(const bf16x8*)&imgI[e0];
            const bf16x8 A1 = *(const bf16x8*)&imgI[8192 + e0];
            #pragma unroll
            for (int ct = 0; ct < 2; ++ct) {
                o[ct] = __builtin_amdgcn_mfma_f32_16x16x32_bf16(A0, Yr[ct][kb], o[ct], 0, 0, 0);
                o[ct] = __builtin_amdgcn_mfma_f32_16x16x32_bf16(A1, Yi[ct][kb], o[ct], 0, 0, 0);
            }
        }
        #pragma unroll
        for (int ct = 0; ct < 2; ++ct) {
            const int c = wv * 32 + ct * 16 + cc;
            #pragma unroll
            for (int reg = 0; reg < 4; ++reg) {
                const int n = mt * 16 + g4 * 4 + reg;
                if (n < SEQ) {
                    const size_t idx = (size_t)n * BD + (size_t)b * DIM + c;
                    out[idx] = x[idx] + o[ct][reg];
                }
            }
        }
    }
}

// ---------------------------------------------------------------------------
extern "C" void kernel_launch(void* const* d_in, const int* in_sizes, int n_in,
                              void* d_out, int out_size, void* d_ws, size_t ws_size,
                              hipStream_t stream)
{
    (void)in_sizes; (void)n_in; (void)out_size; (void)ws_size;
    const float* x    = (const float*)d_in[0];
    const float* cw   = (const float*)d_in[1];
    const float* cwh  = (const float*)d_in[2];
    const float* thrp = (const float*)d_in[3];
    const float* gam  = (const float*)d_in[4];
    const float* bet  = (const float*)d_in[5];
    float* out = (float*)d_out;

    char* ws = (char*)d_ws;
    unsigned short* imgF = (unsigned short*)(ws);                    // 32768 B
    unsigned short* imgI = (unsigned short*)(ws + 32768);            // 32768 B
    unsigned short* Xg   = (unsigned short*)(ws + 65536);            // 67,108,864 B
    float* normE       = (float*)(ws + 65536 + 67108864);            // 417,792 B
    unsigned* hist     = (unsigned*)(ws + 65536 + 67108864 + 417792); // 32768 B
    unsigned* counters = (unsigned*)(ws + 65536 + 67108864 + 417792 + 32768);  // 64 B
    float* thresh      = (float*)(ws + 65536 + 67108864 + 417792 + 32768 + 64);

    k_tables<<<64, 256, 0, stream>>>(imgF, imgI);
    hipMemsetAsync(counters, 0, 64, stream);   // 8 barrier slots, zeroed per replay

    for (int l = 0; l < NLAYER; ++l) {
        const float* xi = (l == 0) ? x : out;
        k_fwd<<<BATCH, 256, 0, stream>>>(xi, gam + l * DIM, bet + l * DIM,
                                         imgF, Xg, normE);
        k_quant<<<NBQ, 256, 0, stream>>>(normE, hist, counters, thrp, l, thresh);
        k_asb<<<BATCH, 256, 0, stream>>>(xi, cw + l * DIM * 2, cwh + l * DIM * 2,
                                         Xg, imgI, normE, thresh, out);
    }
}

// Round 11
// 425.004 us; speedup vs baseline: 1.2347x; 1.0779x over previous
//
#include <hip/hip_runtime.h>
#include <math.h>

#define SEQ    100
#define BATCH  2048
#define DIM    128
#define NF     51
#define NLAYER 2
#define MTOT   (BATCH * NF)
#define BD     (BATCH * DIM)
#define XSTR   16384   // ushorts per batch in Xg: [c(128)][plane(2)][k(64)]
#define NBQ    96      // k_quant grid (all co-resident)

typedef __attribute__((ext_vector_type(8))) short bf16x8;
typedef __attribute__((ext_vector_type(4))) float f32x4v;

__device__ __forceinline__ unsigned cvtpk(float lo, float hi) {
    unsigned r;
    asm("v_cvt_pk_bf16_f32 %0, %1, %2" : "=v"(r) : "v"(lo), "v"(hi));
    return r;
}
__device__ __forceinline__ unsigned short f2bf(float f) {
    unsigned u = __float_as_uint(f);
    return (unsigned short)((u + 0x7FFFu + ((u >> 16) & 1u)) >> 16);
}
__device__ __forceinline__ float bf2f(unsigned short u) {
    return __uint_as_float((unsigned)u << 16);
}

// ---------------------------------------------------------------- tables ---
__global__ void k_tables(unsigned short* __restrict__ imgF,
                         unsigned short* __restrict__ imgI) {
    const int i = blockIdx.x * 256 + threadIdx.x;   // 16384 per table
    const float W = 6.28318530717958647692f / 100.f;
    if (i < 2 * 64 * 128) {
        const int p = i >> 13, k = (i >> 7) & 63, n = i & 127;
        float v = 0.f;
        if (k < NF && n < SEQ) {
            float s, c; sincosf((float)((k * n) % 100) * W, &s, &c);
            v = 0.1f * (p ? -s : c);
        }
        imgF[i] = f2bf(v);
    }
    if (i < 2 * 128 * 64) {
        const int p = i >> 13, n = (i >> 6) & 127, k = i & 63;
        float v = 0.f;
        if (k < NF && n < SEQ) {
            float s, c; sincosf((float)((k * n) % 100) * W, &s, &c);
            const float a = (k == 0 || k == 50) ? 0.1f : 0.2f;
            v = p ? -a * s : a * c;
        }
        imgI[i] = f2bf(v);
    }
}

// ================ shared device pieces (fwd MFMA tail, used twice) =========
// Requires hT staged (bf16 LN output, swizzle chunk^( (c>>1)&7 )).
// After B-frag loads + barrier, hT front is reused as f32 scratch.
__device__ __forceinline__ void fwd_mfma_tail(
    unsigned short* hT, const unsigned short* __restrict__ imgF,
    unsigned short* __restrict__ Xg, float* __restrict__ normE,
    int b, int t, int lane, int wv, int g4, int cc)
{
    bf16x8 Bf[2][4];
    #pragma unroll
    for (int ct = 0; ct < 2; ++ct) {
        const int c = wv * 32 + ct * 16 + cc;
        #pragma unroll
        for (int ks = 0; ks < 4; ++ks)
            Bf[ct][ks] = *(const bf16x8*)&hT[c * 128 + (((ks * 4 + g4) ^ (cc >> 1)) << 3)];
    }
    __syncthreads();   // all hT reads complete -> reuse hT as f32 scratch

    float* epart    = (float*)hT;          // [64][4]
    float* energy_s = (float*)hT + 256;    // [64]
    float* medp     = (float*)hT + 320;    // [1]

    #pragma unroll
    for (int mt = 0; mt < 4; ++mt) {
        const int kr = mt * 16 + cc;
        f32x4v aR[2], aI[2];
        aR[0] = aR[1] = aI[0] = aI[1] = (f32x4v){0.f, 0.f, 0.f, 0.f};
        #pragma unroll
        for (int ks = 0; ks < 4; ++ks) {
            const int e0 = kr * 128 + ks * 32 + g4 * 8;
            const bf16x8 A0 = *(const bf16x8*)&imgF[e0];
            const bf16x8 A1 = *(const bf16x8*)&imgF[8192 + e0];
            #pragma unroll
            for (int ct = 0; ct < 2; ++ct) {
                aR[ct] = __builtin_amdgcn_mfma_f32_16x16x32_bf16(A0, Bf[ct][ks], aR[ct], 0, 0, 0);
                aI[ct] = __builtin_amdgcn_mfma_f32_16x16x32_bf16(A1, Bf[ct][ks], aI[ct], 0, 0, 0);
            }
        }
        #pragma unroll
        for (int reg = 0; reg < 4; ++reg) {
            float e = aR[0][reg] * aR[0][reg] + aI[0][reg] * aI[0][reg]
                    + aR[1][reg] * aR[1][reg] + aI[1][reg] * aI[1][reg];
            e += __shfl_xor(e, 1, 64); e += __shfl_xor(e, 2, 64);
            e += __shfl_xor(e, 4, 64); e += __shfl_xor(e, 8, 64);
            if (cc == 0) epart[(mt * 16 + g4 * 4 + reg) * 4 + wv] = e;
        }
        #pragma unroll
        for (int ct = 0; ct < 2; ++ct) {
            const int c = wv * 32 + ct * 16 + cc;
            unsigned short* Xb = Xg + (size_t)b * XSTR + (size_t)c * 128;
            const int k0 = mt * 16 + g4 * 4;
            uint2 pr, pi;
            pr.x = cvtpk(aR[ct][0], aR[ct][1]); pr.y = cvtpk(aR[ct][2], aR[ct][3]);
            pi.x = cvtpk(aI[ct][0], aI[ct][1]); pi.y = cvtpk(aI[ct][2], aI[ct][3]);
            *(uint2*)&Xb[k0]      = pr;
            *(uint2*)&Xb[64 + k0] = pi;
        }
    }
    __syncthreads();
    if (t < 64) energy_s[t] = epart[4 * t] + epart[4 * t + 1]
                            + epart[4 * t + 2] + epart[4 * t + 3];
    __syncthreads();
    if (t < NF) {
        const float e = energy_s[t];
        int cnt = 0;
        for (int j = 0; j < NF; ++j) {
            const float ej = energy_s[j];
            cnt += (ej < e || (ej == e && j < t)) ? 1 : 0;
        }
        if (cnt == (NF - 1) / 2) *medp = e;
    }
    __syncthreads();
    if (t < NF) normE[b * NF + t] = energy_s[t] / (*medp + 1e-6f);
}

// ------------------- A: LN + fwd DFT + X store (bf16) + energy + normE -----
__global__ __launch_bounds__(256, 5) void k_fwd(
    const float* __restrict__ x,
    const float* __restrict__ gamma, const float* __restrict__ beta,
    const unsigned short* __restrict__ imgF,
    unsigned short* __restrict__ Xg,
    float* __restrict__ normE)
{
    __shared__ __align__(16) unsigned short hT[128 * 128];   // 32 KB exactly

    const int b = blockIdx.x, t = threadIdx.x;
    const int lane = t & 63, wv = t >> 6, g4 = lane >> 4, cc = lane & 15;

    // fused LN + h^T staging (single x fetch; loads hoisted)
    {
        const int c0 = lane * 2;
        const float2 gv = *(const float2*)&gamma[c0];
        const float2 bv = *(const float2*)&beta[c0];
        float2 v[4][8];
        #pragma unroll
        for (int slot = 0; slot < 4; ++slot) {
            const int n0 = (slot * 4 + wv) * 8;
            #pragma unroll
            for (int j = 0; j < 8; ++j)
                if (n0 + j < SEQ)
                    v[slot][j] = *(const float2*)&x[(size_t)(n0 + j) * BD + (size_t)b * DIM + c0];
        }
        #pragma unroll
        for (int slot = 0; slot < 4; ++slot) {
            const int chunk = slot * 4 + wv;       // 0..15
            const int n0 = chunk * 8;
            float he[8], ho[8];
            #pragma unroll
            for (int j = 0; j < 8; ++j) {
                he[j] = 0.f; ho[j] = 0.f;
                if (n0 + j < SEQ) {
                    float s  = v[slot][j].x + v[slot][j].y;
                    float s2 = fmaf(v[slot][j].x, v[slot][j].x, v[slot][j].y * v[slot][j].y);
                    #pragma unroll
                    for (int off = 1; off < 64; off <<= 1) {
                        s  += __shfl_xor(s,  off, 64);
                        s2 += __shfl_xor(s2, off, 64);
                    }
                    const float mu   = s * (1.f / 128.f);
                    const float rstd = rsqrtf(s2 * (1.f / 128.f) - mu * mu + 1e-5f);
                    he[j] = fmaf((v[slot][j].x - mu) * rstd, gv.x, bv.x);
                    ho[j] = fmaf((v[slot][j].y - mu) * rstd, gv.y, bv.y);
                }
            }
            int4 ve, vo;
            ve.x = (int)cvtpk(he[0], he[1]); ve.y = (int)cvtpk(he[2], he[3]);
            ve.z = (int)cvtpk(he[4], he[5]); ve.w = (int)cvtpk(he[6], he[7]);
            vo.x = (int)cvtpk(ho[0], ho[1]); vo.y = (int)cvtpk(ho[2], ho[3]);
            vo.z = (int)cvtpk(ho[4], ho[5]); vo.w = (int)cvtpk(ho[6], ho[7]);
            const int sw = (chunk ^ (lane & 7)) << 3;
            *(int4*)&hT[(c0    ) * 128 + sw] = ve;
            *(int4*)&hT[(c0 + 1) * 128 + sw] = vo;
        }
    }
    __syncthreads();
    fwd_mfma_tail(hT, imgF, Xg, normE, b, t, lane, wv, g4, cc);
}

// ------------------------- fused 3-round radix select (single kernel) ------
__device__ __forceinline__ void gbar(unsigned* slot) {
    __syncthreads();
    __threadfence();
    if (threadIdx.x == 0) {
        __hip_atomic_fetch_add(slot, 1u, __ATOMIC_ACQ_REL, __HIP_MEMORY_SCOPE_AGENT);
        while (__hip_atomic_load(slot, __ATOMIC_ACQUIRE, __HIP_MEMORY_SCOPE_AGENT) < NBQ)
            __builtin_amdgcn_s_sleep(8);
    }
    __syncthreads();
}

__device__ __forceinline__ void scan2(const unsigned* __restrict__ H0,
                                      int bins, int shift, bool entry,
                                      unsigned r0, unsigned* sp, unsigned* sc)
{
    const int t = threadIdx.x;
    if (t < 128) {
        const int j = t >> 6, ln = t & 63;
        const unsigned rk = r0 + (unsigned)j;
        const unsigned oldsp = entry ? sp[j] : 0u;
        const unsigned oldsc = entry ? sc[j] : 0u;
        const unsigned rem = rk - oldsc;
        const unsigned* H = H0 + (entry ? j * bins : 0);
        const int per = bins / 64;
        unsigned sum = 0;
        for (int i = 0; i < per; ++i)
            sum += __hip_atomic_load(&H[ln * per + i], __ATOMIC_RELAXED, __HIP_MEMORY_SCOPE_AGENT);
        unsigned pre = sum;
        #pragma unroll
        for (int off = 1; off < 64; off <<= 1) {
            const unsigned tt = __shfl_up(pre, off, 64);
            if (ln >= off) pre += tt;
        }
        const unsigned excl = pre - sum;
        if (rem >= excl && rem < excl + sum) {
            unsigned cum = excl;
            for (int i = 0; i < per; ++i) {
                const unsigned hc = __hip_atomic_load(&H[ln * per + i],
                                        __ATOMIC_RELAXED, __HIP_MEMORY_SCOPE_AGENT);
                if (rem < cum + hc) {
                    sp[j] = oldsp | ((unsigned)(ln * per + i) << shift);
                    sc[j] = oldsc + cum;
                    break;
                }
                cum += hc;
            }
        }
    }
    __syncthreads();
}

__global__ void k_quant(const float* __restrict__ normE,
                        unsigned* __restrict__ hist,
                        unsigned* __restrict__ counters,
                        const float* __restrict__ thrp,
                        const int layer,
                        float* __restrict__ thresh)
{
    __shared__ unsigned lh[4096];
    __shared__ unsigned sp[2], sc[2];
    const int t = threadIdx.x, bid = blockIdx.x;
    const float q = thrp[layer] * (float)(MTOT - 1);
    const unsigned r0 = (unsigned)floorf(q);
    unsigned* cnt = counters + layer * 4;

    for (int i = bid * 256 + t; i < 8192; i += NBQ * 256) hist[i] = 0u;
    gbar(cnt + 0);

    for (int i = t; i < 2048; i += 256) lh[i] = 0;
    __syncthreads();
    for (int i = bid * 256 + t; i < MTOT; i += NBQ * 256)
        atomicAdd(&lh[__float_as_uint(normE[i]) >> 21], 1u);
    __syncthreads();
    for (int i = t; i < 2048; i += 256) {
        const unsigned c = lh[i];
        if (c) atomicAdd(&hist[i], c);
    }
    gbar(cnt + 1);

    scan2(hist, 2048, 21, false, r0, sp, sc);
    {
        const unsigned p0 = sp[0], p1 = sp[1];
        for (int i = t; i < 4096; i += 256) lh[i] = 0;
        __syncthreads();
        for (int i = bid * 256 + t; i < MTOT; i += NBQ * 256) {
            const unsigned v = __float_as_uint(normE[i]);
            const unsigned bin = (v >> 10) & 2047u;
            if ((v & 0xFFE00000u) == p0) atomicAdd(&lh[bin], 1u);
            if ((v & 0xFFE00000u) == p1) atomicAdd(&lh[2048 + bin], 1u);
        }
        __syncthreads();
        for (int i = t; i < 4096; i += 256) {
            const unsigned c = lh[i];
            if (c) atomicAdd(&hist[2048 + i], c);
        }
    }
    gbar(cnt + 2);

    scan2(hist + 2048, 2048, 10, true, r0, sp, sc);
    {
        const unsigned p0 = sp[0], p1 = sp[1];
        for (int i = t; i < 2048; i += 256) lh[i] = 0;
        __syncthreads();
        for (int i = bid * 256 + t; i < MTOT; i += NBQ * 256) {
            const unsigned v = __float_as_uint(normE[i]);
            const unsigned bin = v & 1023u;
            if ((v & 0xFFFFFC00u) == p0) atomicAdd(&lh[bin], 1u);
            if ((v & 0xFFFFFC00u) == p1) atomicAdd(&lh[1024 + bin], 1u);
        }
        __syncthreads();
        for (int i = t; i < 2048; i += 256) {
            const unsigned c = lh[i];
            if (c) atomicAdd(&hist[6144 + i], c);
        }
    }
    gbar(cnt + 3);

    if (bid == 0) {
        scan2(hist + 6144, 1024, 0, true, r0, sp, sc);
        if (t == 0) {
            const float v0 = __uint_as_float(sp[0]);
            const float v1 = __uint_as_float(sp[1]);
            const float frac = q - floorf(q);
            thresh[0] = v0 * (1.f - frac) + v1 * frac;
        }
    }
}

// ===== C-fused: irfft+residual (layer l) THEN LN+fwd DFT (layer l+1) =======
__global__ __launch_bounds__(256, 4) void k_asb_fwd(
    const float* __restrict__ x,
    const float* __restrict__ cw, const float* __restrict__ cwh,
    const unsigned short* __restrict__ imgI,
    const unsigned short* __restrict__ imgF,
    const float* __restrict__ gamma_n, const float* __restrict__ beta_n,
    float* __restrict__ normE,          // read (layer l mask) AND written (layer l+1)
    const float* __restrict__ thresh,
    float* __restrict__ out,
    unsigned short* __restrict__ Xg)
{
    __shared__ __align__(16) unsigned short hT[128 * 128];   // 32 KB
    __shared__ float mask_s[64];
    __shared__ float part_s[112][4], part_q[112][4];
    __shared__ float2 musv[112];

    const int b = blockIdx.x, t = threadIdx.x;
    const int lane = t & 63, wv = t >> 6, g4 = lane >> 4, cc = lane & 15;

    if (t < 64) mask_s[t] = (t < NF && normE[b * NF + t] < thresh[0]) ? 1.f : 0.f;
    __syncthreads();

    // ---- phase 1: load X, weight, build inverse B-frags (R6-proven) ----
    bf16x8 Yr[2][2], Yi[2][2];
    float gn[2], bn[2];
    #pragma unroll
    for (int ct = 0; ct < 2; ++ct) {
        const int c = wv * 32 + ct * 16 + cc;
        gn[ct] = gamma_n[c]; bn[ct] = beta_n[c];
        const unsigned short* Xb = Xg + (size_t)b * XSTR + (size_t)c * 128;
        const float2 w2 = *(const float2*)&cw[2 * c];
        const float2 h2 = *(const float2*)&cwh[2 * c];
        #pragma unroll
        for (int kb = 0; kb < 2; ++kb) {
            const bf16x8 xr = *(const bf16x8*)&Xb[kb * 32 + g4 * 8];
            const bf16x8 xi = *(const bf16x8*)&Xb[64 + kb * 32 + g4 * 8];
            float yr[8], yi[8];
            #pragma unroll
            for (int j = 0; j < 8; ++j) {
                const float m   = mask_s[kb * 32 + g4 * 8 + j];
                const float fre = fmaf(m, h2.x, w2.x);
                const float fim = fmaf(m, h2.y, w2.y);
                const float fxr = bf2f((unsigned short)xr[j]);
                const float fxi = bf2f((unsigned short)xi[j]);
                yr[j] = fxr * fre - fxi * fim;
                yi[j] = fxr * fim + fxi * fre;
            }
            unsigned ur[4], ui[4];
            #pragma unroll
            for (int jj = 0; jj < 4; ++jj) {
                ur[jj] = cvtpk(yr[2 * jj], yr[2 * jj + 1]);
                ui[jj] = cvtpk(yi[2 * jj], yi[2 * jj + 1]);
            }
            Yr[ct][kb] = *(bf16x8*)ur;
            Yi[ct][kb] = *(bf16x8*)ui;
        }
    }

    // ---- phase 2: inverse DFT + residual + store; RETAIN out in ov ----
    float ov[7][2][4];
    #pragma unroll
    for (int mt = 0; mt < 7; ++mt) {
        const int nr = mt * 16 + cc;
        f32x4v o[2];
        o[0] = o[1] = (f32x4v){0.f, 0.f, 0.f, 0.f};
        #pragma unroll
        for (int kb = 0; kb < 2; ++kb) {
            const int e0 = nr * 64 + kb * 32 + g4 * 8;
            const bf16x8 A0 = *(const bf16x8*)&imgI[e0];
            const bf16x8 A1 = *(const bf16x8*)&imgI[8192 + e0];
            #pragma unroll
            for (int ct = 0; ct < 2; ++ct) {
                o[ct] = __builtin_amdgcn_mfma_f32_16x16x32_bf16(A0, Yr[ct][kb], o[ct], 0, 0, 0);
                o[ct] = __builtin_amdgcn_mfma_f32_16x16x32_bf16(A1, Yi[ct][kb], o[ct], 0, 0, 0);
            }
        }
        #pragma unroll
        for (int ct = 0; ct < 2; ++ct) {
            const int c = wv * 32 + ct * 16 + cc;
            #pragma unroll
            for (int reg = 0; reg < 4; ++reg) {
                const int n = mt * 16 + g4 * 4 + reg;
                float val = 0.f;
                if (n < SEQ) {
                    const size_t idx = (size_t)n * BD + (size_t)b * DIM + c;
                    val = x[idx] + o[ct][reg];
                    out[idx] = val;
                }
                ov[mt][ct][reg] = val;
            }
        }
    }

    // ---- phase 3: next-layer LN stats from registers ----
    #pragma unroll
    for (int mt = 0; mt < 7; ++mt) {
        #pragma unroll
        for (int reg = 0; reg < 4; ++reg) {
            float s  = ov[mt][0][reg] + ov[mt][1][reg];
            float s2 = fmaf(ov[mt][0][reg], ov[mt][0][reg],
                            ov[mt][1][reg] * ov[mt][1][reg]);
            s  += __shfl_xor(s, 1, 64);  s  += __shfl_xor(s, 2, 64);
            s  += __shfl_xor(s, 4, 64);  s  += __shfl_xor(s, 8, 64);
            s2 += __shfl_xor(s2, 1, 64); s2 += __shfl_xor(s2, 2, 64);
            s2 += __shfl_xor(s2, 4, 64); s2 += __shfl_xor(s2, 8, 64);
            if (cc == 0) {
                const int n = mt * 16 + g4 * 4 + reg;
                part_s[n][wv] = s; part_q[n][wv] = s2;
            }
        }
    }
    __syncthreads();
    if (t < 112) {
        const float s  = part_s[t][0] + part_s[t][1] + part_s[t][2] + part_s[t][3];
        const float sq = part_q[t][0] + part_q[t][1] + part_q[t][2] + part_q[t][3];
        const float mu = s * (1.f / 128.f);
        const float rstd = rsqrtf(sq * (1.f / 128.f) - mu * mu + 1e-5f);
        musv[t] = make_float2(mu, rstd);
    }
    __syncthreads();

    // ---- phase 4: stage bf16 LN(out) into hT (+ zero-fill n in [112,128)) --
    {
        const int cf = t >> 1, chf = 14 + (t & 1);
        *(int4*)&hT[cf * 128 + ((chf ^ ((cf >> 1) & 7)) << 3)] = (int4){0, 0, 0, 0};
    }
    #pragma unroll
    for (int mt = 0; mt < 7; ++mt) {
        #pragma unroll
        for (int ct = 0; ct < 2; ++ct) {
            const int c = wv * 32 + ct * 16 + cc;
            #pragma unroll
            for (int pr = 0; pr < 2; ++pr) {
                const int n0 = mt * 16 + g4 * 4 + pr * 2;
                float h0 = 0.f, h1 = 0.f;
                if (n0 < SEQ) {
                    const float2 ms = musv[n0];
                    h0 = fmaf((ov[mt][ct][pr * 2] - ms.x) * ms.y, gn[ct], bn[ct]);
                }
                if (n0 + 1 < SEQ) {
                    const float2 ms = musv[n0 + 1];
                    h1 = fmaf((ov[mt][ct][pr * 2 + 1] - ms.x) * ms.y, gn[ct], bn[ct]);
                }
                const unsigned u = cvtpk(h0, h1);
                const int e = c * 128 + (((n0 >> 3) ^ ((c >> 1) & 7)) << 3) + (n0 & 7);
                *(unsigned*)&hT[e] = u;
            }
        }
    }
    __syncthreads();

    // ---- phase 5: fwd DFT + energy + median + normE (shared tail) ----
    fwd_mfma_tail(hT, imgF, Xg, normE, b, t, lane, wv, g4, cc);
}

// --------------- C-final: load X + weight + irfft + residual ---------------
__global__ __launch_bounds__(256, 4) void k_asb(
    const float* __restrict__ x,
    const float* __restrict__ cw, const float* __restrict__ cwh,
    const unsigned short* __restrict__ Xg,
    const unsigned short* __restrict__ imgI,
    const float* __restrict__ normE, const float* __restrict__ thresh,
    float* __restrict__ out)
{
    __shared__ __align__(16) float mask_s[64];

    const int b = blockIdx.x, t = threadIdx.x;
    const int lane = t & 63, wv = t >> 6, g4 = lane >> 4, cc = lane & 15;

    if (t < 64) mask_s[t] = (t < NF && normE[b * NF + t] < thresh[0]) ? 1.f : 0.f;
    __syncthreads();

    bf16x8 Yr[2][2], Yi[2][2];
    #pragma unroll
    for (int ct = 0; ct < 2; ++ct) {
        const int c = wv * 32 + ct * 16 + cc;
        const unsigned short* Xb = Xg + (size_t)b * XSTR + (size_t)c * 128;
        const float2 w2 = *(const float2*)&cw[2 * c];
        const float2 h2 = *(const float2*)&cwh[2 * c];
        #pragma unroll
        for (int kb = 0; kb < 2; ++kb) {
            const bf16x8 xr = *(const bf16x8*)&Xb[kb * 32 + g4 * 8];
            const bf16x8 xi = *(const bf16x8*)&Xb[64 + kb * 32 + g4 * 8];
            float yr[8], yi[8];
            #pragma unroll
            for (int j = 0; j < 8; ++j) {
                const float m   = mask_s[kb * 32 + g4 * 8 + j];
                const float fre = fmaf(m, h2.x, w2.x);
                const float fim = fmaf(m, h2.y, w2.y);
                const float fxr = bf2f((unsigned short)xr[j]);
                const float fxi = bf2f((unsigned short)xi[j]);
                yr[j] = fxr * fre - fxi * fim;
                yi[j] = fxr * fim + fxi * fre;
            }
            unsigned ur[4], ui[4];
            #pragma unroll
            for (int jj = 0; jj < 4; ++jj) {
                ur[jj] = cvtpk(yr[2 * jj], yr[2 * jj + 1]);
                ui[jj] = cvtpk(yi[2 * jj], yi[2 * jj + 1]);
            }
            Yr[ct][kb] = *(bf16x8*)ur;
            Yi[ct][kb] = *(bf16x8*)ui;
        }
    }

    #pragma unroll
    for (int mt = 0; mt < 7; ++mt) {
        const int nr = mt * 16 + cc;
        f32x4v o[2];
        o[0] = o[1] = (f32x4v){0.f, 0.f, 0.f, 0.f};
        #pragma unroll
        for (int kb = 0; kb < 2; ++kb) {
            const int e0 = nr * 64 + kb * 32 + g4 * 8;
            const bf16x8 A0 = *(const bf16x8*)&imgI[e0];
            const bf16x8 A1 = *(const bf16x8*)&imgI[8192 + e0];
            #pragma unroll
            for (int ct = 0; ct < 2; ++ct) {
                o[ct] = __builtin_amdgcn_mfma_f32_16x16x32_bf16(A0, Yr[ct][kb], o[ct], 0, 0, 0);
                o[ct] = __builtin_amdgcn_mfma_f32_16x16x32_bf16(A1, Yi[ct][kb], o[ct], 0, 0, 0);
            }
        }
        #pragma unroll
        for (int ct = 0; ct < 2; ++ct) {
            const int c = wv * 32 + ct * 16 + cc;
            #pragma unroll
            for (int reg = 0; reg < 4; ++reg) {
                const int n = mt * 16 + g4 * 4 + reg;
                if (n < SEQ) {
                    const size_t idx = (size_t)n * BD + (size_t)b * DIM + c;
                    out[idx] = x[idx] + o[ct][reg];
                }
            }
        }
    }
}

// ---------------------------------------------------------------------------
extern "C" void kernel_launch(void* const* d_in, const int* in_sizes, int n_in,
                              void* d_out, int out_size, void* d_ws, size_t ws_size,
                              hipStream_t stream)
{
    (void)in_sizes; (void)n_in; (void)out_size; (void)ws_size;
    const float* x    = (const float*)d_in[0];
    const float* cw   = (const float*)d_in[1];
    const float* cwh  = (const float*)d_in[2];
    const float* thrp = (const float*)d_in[3];
    const float* gam  = (const float*)d_in[4];
    const float* bet  = (const float*)d_in[5];
    float* out = (float*)d_out;

    char* ws = (char*)d_ws;
    unsigned short* imgF = (unsigned short*)(ws);                    // 32768 B
    unsigned short* imgI = (unsigned short*)(ws + 32768);            // 32768 B
    unsigned short* Xg   = (unsigned short*)(ws + 65536);            // 67,108,864 B
    float* normE       = (float*)(ws + 65536 + 67108864);            // 417,792 B
    unsigned* hist     = (unsigned*)(ws + 65536 + 67108864 + 417792); // 32768 B
    unsigned* counters = (unsigned*)(ws + 65536 + 67108864 + 417792 + 32768);  // 64 B
    float* thresh      = (float*)(ws + 65536 + 67108864 + 417792 + 32768 + 64);

    k_tables<<<64, 256, 0, stream>>>(imgF, imgI);
    (void)hipMemsetAsync(counters, 0, 64, stream);   // 8 barrier slots, zeroed per replay

    // layer 0 fwd
    k_fwd<<<BATCH, 256, 0, stream>>>(x, gam, bet, imgF, Xg, normE);
    k_quant<<<NBQ, 256, 0, stream>>>(normE, hist, counters, thrp, 0, thresh);
    // layer 0 asb + layer 1 fwd (fused)
    k_asb_fwd<<<BATCH, 256, 0, stream>>>(x, cw, cwh, imgI, imgF,
                                         gam + DIM, bet + DIM,
                                         normE, thresh, out, Xg);
    k_quant<<<NBQ, 256, 0, stream>>>(normE, hist, counters, thrp, 1, thresh);
    // layer 1 asb (final)
    k_asb<<<BATCH, 256, 0, stream>>>(out, cw + DIM * 2, cwh + DIM * 2,
                                     Xg, imgI, normE, thresh, out);
}

// Round 12
// 399.848 us; speedup vs baseline: 1.3124x; 1.0629x over previous
//
#include <hip/hip_runtime.h>
#include <math.h>

#define SEQ    100
#define BATCH  2048
#define DIM    128
#define NF     51
#define NLAYER 2
#define MTOT   (BATCH * NF)
#define BD     (BATCH * DIM)
#define XSTR   16384   // ushorts per batch in Xg: [c(128)][plane(2)][k(64)]

typedef __attribute__((ext_vector_type(8))) short bf16x8;
typedef __attribute__((ext_vector_type(4))) float f32x4v;

__device__ __forceinline__ unsigned cvtpk(float lo, float hi) {
    unsigned r;
    asm("v_cvt_pk_bf16_f32 %0, %1, %2" : "=v"(r) : "v"(lo), "v"(hi));
    return r;
}
__device__ __forceinline__ unsigned short f2bf(float f) {
    unsigned u = __float_as_uint(f);
    return (unsigned short)((u + 0x7FFFu + ((u >> 16) & 1u)) >> 16);
}
__device__ __forceinline__ float bf2f(unsigned short u) {
    return __uint_as_float((unsigned)u << 16);
}

// ---------------------------------------------------------------- tables ---
// imgF [p][k(64)][n(128)] bf16: p0 = 0.1*cos(2pi k n/100), p1 = -0.1*sin; 0-pad.
// imgI [p][n(128)][k(64)] bf16: p0 = a_k*cos, p1 = -a_k*sin; a_k = 0.1/0.2.
__global__ void k_tables(unsigned short* __restrict__ imgF,
                         unsigned short* __restrict__ imgI) {
    const int i = blockIdx.x * 256 + threadIdx.x;   // 16384 per table
    const float W = 6.28318530717958647692f / 100.f;
    if (i < 2 * 64 * 128) {
        const int p = i >> 13, k = (i >> 7) & 63, n = i & 127;
        float v = 0.f;
        if (k < NF && n < SEQ) {
            float s, c; sincosf((float)((k * n) % 100) * W, &s, &c);
            v = 0.1f * (p ? -s : c);
        }
        imgF[i] = f2bf(v);
    }
    if (i < 2 * 128 * 64) {
        const int p = i >> 13, n = (i >> 6) & 127, k = i & 63;
        float v = 0.f;
        if (k < NF && n < SEQ) {
            float s, c; sincosf((float)((k * n) % 100) * W, &s, &c);
            const float a = (k == 0 || k == 50) ? 0.1f : 0.2f;
            v = p ? -a * s : a * c;
        }
        imgI[i] = f2bf(v);
    }
}

// ------------------- A: LN + fwd DFT + X store (bf16) + energy + normE -----
// R6-proven structure: 34 KB LDS, (256,4), single hoisted x fetch.
__global__ __launch_bounds__(256, 4) void k_fwd(
    const float* __restrict__ x,
    const float* __restrict__ gamma, const float* __restrict__ beta,
    const unsigned short* __restrict__ imgF,
    unsigned short* __restrict__ Xg,   // [BATCH][c][plane][k64] bf16
    float* __restrict__ normE)
{
    __shared__ __align__(16) unsigned short hT[128 * 128];   // 32 KB
    __shared__ float epart[64][4];
    __shared__ float energy_s[64];
    __shared__ float med_s;

    const int b = blockIdx.x, t = threadIdx.x;
    const int lane = t & 63, wv = t >> 6, g4 = lane >> 4, cc = lane & 15;

    // ---- fused LN + h^T staging (single x fetch; loads hoisted) ----
    {
        const int c0 = lane * 2;
        const float2 gv = *(const float2*)&gamma[c0];
        const float2 bv = *(const float2*)&beta[c0];
        float2 v[4][8];
        #pragma unroll
        for (int slot = 0; slot < 4; ++slot) {
            const int n0 = (slot * 4 + wv) * 8;
            #pragma unroll
            for (int j = 0; j < 8; ++j)
                if (n0 + j < SEQ)
                    v[slot][j] = *(const float2*)&x[(size_t)(n0 + j) * BD + (size_t)b * DIM + c0];
        }
        #pragma unroll
        for (int slot = 0; slot < 4; ++slot) {
            const int chunk = slot * 4 + wv;       // 0..15
            const int n0 = chunk * 8;
            float he[8], ho[8];
            #pragma unroll
            for (int j = 0; j < 8; ++j) {
                he[j] = 0.f; ho[j] = 0.f;
                if (n0 + j < SEQ) {
                    float s  = v[slot][j].x + v[slot][j].y;
                    float s2 = fmaf(v[slot][j].x, v[slot][j].x, v[slot][j].y * v[slot][j].y);
                    #pragma unroll
                    for (int off = 1; off < 64; off <<= 1) {
                        s  += __shfl_xor(s,  off, 64);
                        s2 += __shfl_xor(s2, off, 64);
                    }
                    const float mu   = s * (1.f / 128.f);
                    const float rstd = rsqrtf(s2 * (1.f / 128.f) - mu * mu + 1e-5f);
                    he[j] = fmaf((v[slot][j].x - mu) * rstd, gv.x, bv.x);
                    ho[j] = fmaf((v[slot][j].y - mu) * rstd, gv.y, bv.y);
                }
            }
            int4 ve, vo;
            ve.x = (int)cvtpk(he[0], he[1]); ve.y = (int)cvtpk(he[2], he[3]);
            ve.z = (int)cvtpk(he[4], he[5]); ve.w = (int)cvtpk(he[6], he[7]);
            vo.x = (int)cvtpk(ho[0], ho[1]); vo.y = (int)cvtpk(ho[2], ho[3]);
            vo.z = (int)cvtpk(ho[4], ho[5]); vo.w = (int)cvtpk(ho[6], ho[7]);
            const int sw = (chunk ^ (lane & 7)) << 3;   // swizzle f(c)=(c>>1)&7
            *(int4*)&hT[(c0    ) * 128 + sw] = ve;
            *(int4*)&hT[(c0 + 1) * 128 + sw] = vo;
        }
    }
    __syncthreads();

    // B-fragments: wave's 2 c-tiles
    bf16x8 Bf[2][4];
    #pragma unroll
    for (int ct = 0; ct < 2; ++ct) {
        const int c = wv * 32 + ct * 16 + cc;
        #pragma unroll
        for (int ks = 0; ks < 4; ++ks)
            Bf[ct][ks] = *(const bf16x8*)&hT[c * 128 + (((ks * 4 + g4) ^ (cc >> 1)) << 3)];
    }

    #pragma unroll
    for (int mt = 0; mt < 4; ++mt) {
        const int kr = mt * 16 + cc;
        f32x4v aR[2], aI[2];
        aR[0] = aR[1] = aI[0] = aI[1] = (f32x4v){0.f, 0.f, 0.f, 0.f};
        #pragma unroll
        for (int ks = 0; ks < 4; ++ks) {
            const int e0 = kr * 128 + ks * 32 + g4 * 8;
            const bf16x8 A0 = *(const bf16x8*)&imgF[e0];
            const bf16x8 A1 = *(const bf16x8*)&imgF[8192 + e0];
            #pragma unroll
            for (int ct = 0; ct < 2; ++ct) {
                aR[ct] = __builtin_amdgcn_mfma_f32_16x16x32_bf16(A0, Bf[ct][ks], aR[ct], 0, 0, 0);
                aI[ct] = __builtin_amdgcn_mfma_f32_16x16x32_bf16(A1, Bf[ct][ks], aI[ct], 0, 0, 0);
            }
        }
        // energy partials (f32, before bf16 rounding)
        #pragma unroll
        for (int reg = 0; reg < 4; ++reg) {
            float e = aR[0][reg] * aR[0][reg] + aI[0][reg] * aI[0][reg]
                    + aR[1][reg] * aR[1][reg] + aI[1][reg] * aI[1][reg];
            e += __shfl_xor(e, 1, 64); e += __shfl_xor(e, 2, 64);
            e += __shfl_xor(e, 4, 64); e += __shfl_xor(e, 8, 64);
            if (cc == 0) epart[mt * 16 + g4 * 4 + reg][wv] = e;
        }
        // X store: acc (k=mt*16+g4*4+reg, c) -> Xg[b][c][plane][k] packed bf16
        #pragma unroll
        for (int ct = 0; ct < 2; ++ct) {
            const int c = wv * 32 + ct * 16 + cc;
            unsigned short* Xb = Xg + (size_t)b * XSTR + (size_t)c * 128;
            const int k0 = mt * 16 + g4 * 4;
            uint2 pr, pi;
            pr.x = cvtpk(aR[ct][0], aR[ct][1]); pr.y = cvtpk(aR[ct][2], aR[ct][3]);
            pi.x = cvtpk(aI[ct][0], aI[ct][1]); pi.y = cvtpk(aI[ct][2], aI[ct][3]);
            *(uint2*)&Xb[k0]      = pr;   // plane 0 (Re)
            *(uint2*)&Xb[64 + k0] = pi;   // plane 1 (Im)
        }
    }
    __syncthreads();
    if (t < 64) energy_s[t] = epart[t][0] + epart[t][1] + epart[t][2] + epart[t][3];
    __syncthreads();
    if (t < NF) {
        const float e = energy_s[t];
        int cnt = 0;
        for (int j = 0; j < NF; ++j) {
            const float ej = energy_s[j];
            cnt += (ej < e || (ej == e && j < t)) ? 1 : 0;
        }
        if (cnt == (NF - 1) / 2) med_s = e;
    }
    __syncthreads();
    if (t < NF) normE[b * NF + t] = energy_s[t] / (med_s + 1e-6f);
}

// ----------------------- radix round 0: LDS-aggregated histogram ----------
__global__ void k_hist0(const float* __restrict__ normE,
                        unsigned* __restrict__ hist)
{
    __shared__ unsigned lh[2048];
    for (int i = threadIdx.x; i < 2048; i += 256) lh[i] = 0;
    __syncthreads();
    for (int i = blockIdx.x * 256 + threadIdx.x; i < MTOT; i += gridDim.x * 256)
        atomicAdd(&lh[__float_as_uint(normE[i]) >> 21], 1u);
    __syncthreads();
    for (int i = threadIdx.x; i < 2048; i += 256) {
        const unsigned c = lh[i];
        if (c) atomicAdd(&hist[i], c);
    }
}

// --------------------------- radix select rounds 1 & 2 (fused hist+scan) ---
// hist layout (u32): [0,2048) round0 | [2048,6144) round1 (2 ranks) |
//                    [6144,8192) round2 (2 ranks). done: slot per (layer,phase).
__global__ void k_sel(const float* __restrict__ normE,
                      unsigned* __restrict__ hist,
                      unsigned* __restrict__ sel,
                      unsigned* __restrict__ done,
                      const float* __restrict__ thrp,
                      const int layer, const int phase,
                      float* __restrict__ thresh)
{
    __shared__ unsigned lh[4096];
    __shared__ unsigned sp[2], sc[2];
    __shared__ unsigned ticket_s;
    __shared__ float vb[2];
    const int t = threadIdx.x;
    const float q = thrp[layer] * (float)(MTOT - 1);
    const unsigned r0 = (unsigned)floorf(q);

    if (phase == 1) {
        // entry scan of round-0 hist (2048 bins, shift 21, prefix 0)
        if (t < 128) {
            const int j = t >> 6, ln = t & 63;
            const unsigned rk = r0 + (unsigned)j;
            unsigned sum = 0;
            for (int i = 0; i < 32; ++i) sum += hist[ln * 32 + i];
            unsigned pre = sum;
            #pragma unroll
            for (int off = 1; off < 64; off <<= 1) {
                const unsigned tt = __shfl_up(pre, off, 64);
                if (ln >= off) pre += tt;
            }
            const unsigned excl = pre - sum;
            if (rk >= excl && rk < excl + sum) {
                unsigned cum = excl;
                for (int i = 0; i < 32; ++i) {
                    const unsigned hc = hist[ln * 32 + i];
                    if (rk < cum + hc) { sp[j] = (unsigned)(ln * 32 + i) << 21; sc[j] = cum; break; }
                    cum += hc;
                }
            }
        }
    } else {
        if (t < 2) { sp[t] = sel[2 * t]; sc[t] = sel[2 * t + 1]; }
    }
    __syncthreads();
    const unsigned p0 = sp[0], p1 = sp[1];
    const int bins      = (phase == 1) ? 2048 : 1024;
    const int shift     = (phase == 1) ? 10 : 0;
    const unsigned hmsk = (phase == 1) ? 0xFFE00000u : 0xFFFFFC00u;
    const int region    = (phase == 1) ? 2048 : 6144;

    for (int i = t; i < 2 * bins; i += 256) lh[i] = 0;
    __syncthreads();
    for (int i = blockIdx.x * 256 + t; i < MTOT; i += gridDim.x * 256) {
        const unsigned v = __float_as_uint(normE[i]);
        const unsigned bin = (v >> shift) & (unsigned)(bins - 1);
        if ((v & hmsk) == p0) atomicAdd(&lh[bin], 1u);
        if ((v & hmsk) == p1) atomicAdd(&lh[bins + bin], 1u);
    }
    __syncthreads();
    for (int i = t; i < 2 * bins; i += 256) {
        const unsigned c = lh[i];
        if (c) atomicAdd(&hist[region + i], c);
    }
    __threadfence();
    if (t == 0) ticket_s = atomicAdd(&done[(layer << 1) + (phase - 1)], 1u);
    __syncthreads();
    if (ticket_s != (unsigned)(gridDim.x - 1)) return;
    __threadfence();

    // last block: scan both ranks of this round
    if (t < 128) {
        const int j = t >> 6, ln = t & 63;
        const unsigned rk  = r0 + (unsigned)j;
        const unsigned rem = rk - sc[j];
        const unsigned* H  = hist + region + j * bins;
        const int per = bins / 64;
        unsigned sum = 0;
        for (int i = 0; i < per; ++i)
            sum += __hip_atomic_load(&H[ln * per + i], __ATOMIC_RELAXED, __HIP_MEMORY_SCOPE_AGENT);
        unsigned pre = sum;
        #pragma unroll
        for (int off = 1; off < 64; off <<= 1) {
            const unsigned tt = __shfl_up(pre, off, 64);
            if (ln >= off) pre += tt;
        }
        const unsigned excl = pre - sum;
        if (rem >= excl && rem < excl + sum) {
            unsigned cum = excl;
            for (int i = 0; i < per; ++i) {
                const unsigned hc = __hip_atomic_load(&H[ln * per + i],
                                        __ATOMIC_RELAXED, __HIP_MEMORY_SCOPE_AGENT);
                if (rem < cum + hc) {
                    const unsigned bin = (unsigned)(ln * per + i);
                    if (phase == 1) { sel[2 * j] = sp[j] | (bin << 10); sel[2 * j + 1] = sc[j] + cum; }
                    else            vb[j] = __uint_as_float(sp[j] | bin);
                    break;
                }
                cum += hc;
            }
        }
    }
    __syncthreads();
    if (phase == 1) { for (int i = t; i < 6144; i += 256) hist[i] = 0u; }
    else            { for (int i = t; i < 2048; i += 256) hist[6144 + i] = 0u; }
    if (t == 0 && phase == 2) {
        const float frac = q - floorf(q);
        thresh[0] = vb[0] * (1.f - frac) + vb[1] * frac;
    }
}

// ===== C-fused: irfft+residual (layer l) THEN LN+fwd DFT (layer l+1) =======
__global__ __launch_bounds__(256, 4) void k_asb_fwd(
    const float* __restrict__ x,
    const float* __restrict__ cw, const float* __restrict__ cwh,
    const unsigned short* __restrict__ imgI,
    const unsigned short* __restrict__ imgF,
    const float* __restrict__ gamma_n, const float* __restrict__ beta_n,
    float* __restrict__ normE,          // read (layer l mask) AND written (layer l+1)
    const float* __restrict__ thresh,
    float* __restrict__ out,
    unsigned short* __restrict__ Xg)
{
    __shared__ __align__(16) unsigned short hT[128 * 128];   // 32 KB
    __shared__ float mask_s[64];
    __shared__ float part_s[112][4], part_q[112][4];
    __shared__ float2 musv[112];

    const int b = blockIdx.x, t = threadIdx.x;
    const int lane = t & 63, wv = t >> 6, g4 = lane >> 4, cc = lane & 15;

    if (t < 64) mask_s[t] = (t < NF && normE[b * NF + t] < thresh[0]) ? 1.f : 0.f;
    __syncthreads();

    // ---- phase 1: load X, weight, build inverse B-frags ----
    bf16x8 Yr[2][2], Yi[2][2];
    float gn[2], bn[2];
    #pragma unroll
    for (int ct = 0; ct < 2; ++ct) {
        const int c = wv * 32 + ct * 16 + cc;
        gn[ct] = gamma_n[c]; bn[ct] = beta_n[c];
        const unsigned short* Xb = Xg + (size_t)b * XSTR + (size_t)c * 128;
        const float2 w2 = *(const float2*)&cw[2 * c];
        const float2 h2 = *(const float2*)&cwh[2 * c];
        #pragma unroll
        for (int kb = 0; kb < 2; ++kb) {
            const bf16x8 xr = *(const bf16x8*)&Xb[kb * 32 + g4 * 8];
            const bf16x8 xi = *(const bf16x8*)&Xb[64 + kb * 32 + g4 * 8];
            float yr[8], yi[8];
            #pragma unroll
            for (int j = 0; j < 8; ++j) {
                const float m   = mask_s[kb * 32 + g4 * 8 + j];
                const float fre = fmaf(m, h2.x, w2.x);
                const float fim = fmaf(m, h2.y, w2.y);
                const float fxr = bf2f((unsigned short)xr[j]);
                const float fxi = bf2f((unsigned short)xi[j]);
                yr[j] = fxr * fre - fxi * fim;
                yi[j] = fxr * fim + fxi * fre;
            }
            unsigned ur[4], ui[4];
            #pragma unroll
            for (int jj = 0; jj < 4; ++jj) {
                ur[jj] = cvtpk(yr[2 * jj], yr[2 * jj + 1]);
                ui[jj] = cvtpk(yi[2 * jj], yi[2 * jj + 1]);
            }
            Yr[ct][kb] = *(bf16x8*)ur;
            Yi[ct][kb] = *(bf16x8*)ui;
        }
    }

    // ---- phase 2: inverse DFT + residual + store; RETAIN out in ov ----
    float ov[7][2][4];
    #pragma unroll
    for (int mt = 0; mt < 7; ++mt) {
        const int nr = mt * 16 + cc;
        f32x4v o[2];
        o[0] = o[1] = (f32x4v){0.f, 0.f, 0.f, 0.f};
        #pragma unroll
        for (int kb = 0; kb < 2; ++kb) {
            const int e0 = nr * 64 + kb * 32 + g4 * 8;
            const bf16x8 A0 = *(const bf16x8*)&imgI[e0];
            const bf16x8 A1 = *(const bf16x8*)&imgI[8192 + e0];
            #pragma unroll
            for (int ct = 0; ct < 2; ++ct) {
                o[ct] = __builtin_amdgcn_mfma_f32_16x16x32_bf16(A0, Yr[ct][kb], o[ct], 0, 0, 0);
                o[ct] = __builtin_amdgcn_mfma_f32_16x16x32_bf16(A1, Yi[ct][kb], o[ct], 0, 0, 0);
            }
        }
        #pragma unroll
        for (int ct = 0; ct < 2; ++ct) {
            const int c = wv * 32 + ct * 16 + cc;
            #pragma unroll
            for (int reg = 0; reg < 4; ++reg) {
                const int n = mt * 16 + g4 * 4 + reg;
                float val = 0.f;
                if (n < SEQ) {
                    const size_t idx = (size_t)n * BD + (size_t)b * DIM + c;
                    val = x[idx] + o[ct][reg];
                    out[idx] = val;
                }
                ov[mt][ct][reg] = val;
            }
        }
    }

    // ---- phase 3: next-layer LN stats from registers ----
    #pragma unroll
    for (int mt = 0; mt < 7; ++mt) {
        #pragma unroll
        for (int reg = 0; reg < 4; ++reg) {
            float s  = ov[mt][0][reg] + ov[mt][1][reg];
            float s2 = fmaf(ov[mt][0][reg], ov[mt][0][reg],
                            ov[mt][1][reg] * ov[mt][1][reg]);
            s  += __shfl_xor(s, 1, 64);  s  += __shfl_xor(s, 2, 64);
            s  += __shfl_xor(s, 4, 64);  s  += __shfl_xor(s, 8, 64);
            s2 += __shfl_xor(s2, 1, 64); s2 += __shfl_xor(s2, 2, 64);
            s2 += __shfl_xor(s2, 4, 64); s2 += __shfl_xor(s2, 8, 64);
            if (cc == 0) {
                const int n = mt * 16 + g4 * 4 + reg;
                part_s[n][wv] = s; part_q[n][wv] = s2;
            }
        }
    }
    __syncthreads();
    if (t < 112) {
        const float s  = part_s[t][0] + part_s[t][1] + part_s[t][2] + part_s[t][3];
        const float sq = part_q[t][0] + part_q[t][1] + part_q[t][2] + part_q[t][3];
        const float mu = s * (1.f / 128.f);
        const float rstd = rsqrtf(sq * (1.f / 128.f) - mu * mu + 1e-5f);
        musv[t] = make_float2(mu, rstd);
    }
    __syncthreads();

    // ---- phase 4: stage bf16 LN(out) into hT (+ zero-fill n in [112,128)) --
    {
        const int cf = t >> 1, chf = 14 + (t & 1);
        *(int4*)&hT[cf * 128 + ((chf ^ ((cf >> 1) & 7)) << 3)] = (int4){0, 0, 0, 0};
    }
    #pragma unroll
    for (int mt = 0; mt < 7; ++mt) {
        #pragma unroll
        for (int ct = 0; ct < 2; ++ct) {
            const int c = wv * 32 + ct * 16 + cc;
            #pragma unroll
            for (int pr = 0; pr < 2; ++pr) {
                const int n0 = mt * 16 + g4 * 4 + pr * 2;
                float h0 = 0.f, h1 = 0.f;
                if (n0 < SEQ) {
                    const float2 ms = musv[n0];
                    h0 = fmaf((ov[mt][ct][pr * 2] - ms.x) * ms.y, gn[ct], bn[ct]);
                }
                if (n0 + 1 < SEQ) {
                    const float2 ms = musv[n0 + 1];
                    h1 = fmaf((ov[mt][ct][pr * 2 + 1] - ms.x) * ms.y, gn[ct], bn[ct]);
                }
                const unsigned u = cvtpk(h0, h1);
                const int e = c * 128 + (((n0 >> 3) ^ ((c >> 1) & 7)) << 3) + (n0 & 7);
                *(unsigned*)&hT[e] = u;
            }
        }
    }
    __syncthreads();

    // ---- phase 5: fwd DFT + energy + median + normE (hT-union tail) ----
    {
        bf16x8 Bf[2][4];
        #pragma unroll
        for (int ct = 0; ct < 2; ++ct) {
            const int c = wv * 32 + ct * 16 + cc;
            #pragma unroll
            for (int ks = 0; ks < 4; ++ks)
                Bf[ct][ks] = *(const bf16x8*)&hT[c * 128 + (((ks * 4 + g4) ^ (cc >> 1)) << 3)];
        }
        __syncthreads();   // hT dead -> reuse front as f32 scratch

        float* epart    = (float*)hT;          // [64][4]
        float* energy_s = (float*)hT + 256;    // [64]
        float* medp     = (float*)hT + 320;    // [1]

        #pragma unroll
        for (int mt = 0; mt < 4; ++mt) {
            const int kr = mt * 16 + cc;
            f32x4v aR[2], aI[2];
            aR[0] = aR[1] = aI[0] = aI[1] = (f32x4v){0.f, 0.f, 0.f, 0.f};
            #pragma unroll
            for (int ks = 0; ks < 4; ++ks) {
                const int e0 = kr * 128 + ks * 32 + g4 * 8;
                const bf16x8 A0 = *(const bf16x8*)&imgF[e0];
                const bf16x8 A1 = *(const bf16x8*)&imgF[8192 + e0];
                #pragma unroll
                for (int ct = 0; ct < 2; ++ct) {
                    aR[ct] = __builtin_amdgcn_mfma_f32_16x16x32_bf16(A0, Bf[ct][ks], aR[ct], 0, 0, 0);
                    aI[ct] = __builtin_amdgcn_mfma_f32_16x16x32_bf16(A1, Bf[ct][ks], aI[ct], 0, 0, 0);
                }
            }
            #pragma unroll
            for (int reg = 0; reg < 4; ++reg) {
                float e = aR[0][reg] * aR[0][reg] + aI[0][reg] * aI[0][reg]
                        + aR[1][reg] * aR[1][reg] + aI[1][reg] * aI[1][reg];
                e += __shfl_xor(e, 1, 64); e += __shfl_xor(e, 2, 64);
                e += __shfl_xor(e, 4, 64); e += __shfl_xor(e, 8, 64);
                if (cc == 0) epart[(mt * 16 + g4 * 4 + reg) * 4 + wv] = e;
            }
            #pragma unroll
            for (int ct = 0; ct < 2; ++ct) {
                const int c = wv * 32 + ct * 16 + cc;
                unsigned short* Xb = Xg + (size_t)b * XSTR + (size_t)c * 128;
                const int k0 = mt * 16 + g4 * 4;
                uint2 pr, pi;
                pr.x = cvtpk(aR[ct][0], aR[ct][1]); pr.y = cvtpk(aR[ct][2], aR[ct][3]);
                pi.x = cvtpk(aI[ct][0], aI[ct][1]); pi.y = cvtpk(aI[ct][2], aI[ct][3]);
                *(uint2*)&Xb[k0]      = pr;
                *(uint2*)&Xb[64 + k0] = pi;
            }
        }
        __syncthreads();
        if (t < 64) energy_s[t] = epart[4 * t] + epart[4 * t + 1]
                                + epart[4 * t + 2] + epart[4 * t + 3];
        __syncthreads();
        if (t < NF) {
            const float e = energy_s[t];
            int cnt = 0;
            for (int j = 0; j < NF; ++j) {
                const float ej = energy_s[j];
                cnt += (ej < e || (ej == e && j < t)) ? 1 : 0;
            }
            if (cnt == (NF - 1) / 2) *medp = e;
        }
        __syncthreads();
        if (t < NF) normE[b * NF + t] = energy_s[t] / (*medp + 1e-6f);
    }
}

// --------------- C-final: load X + weight + irfft + residual ---------------
__global__ __launch_bounds__(256, 4) void k_asb(
    const float* __restrict__ x,
    const float* __restrict__ cw, const float* __restrict__ cwh,
    const unsigned short* __restrict__ Xg,
    const unsigned short* __restrict__ imgI,
    const float* __restrict__ normE, const float* __restrict__ thresh,
    float* __restrict__ out)
{
    __shared__ __align__(16) float mask_s[64];

    const int b = blockIdx.x, t = threadIdx.x;
    const int lane = t & 63, wv = t >> 6, g4 = lane >> 4, cc = lane & 15;

    if (t < 64) mask_s[t] = (t < NF && normE[b * NF + t] < thresh[0]) ? 1.f : 0.f;
    __syncthreads();

    bf16x8 Yr[2][2], Yi[2][2];
    #pragma unroll
    for (int ct = 0; ct < 2; ++ct) {
        const int c = wv * 32 + ct * 16 + cc;
        const unsigned short* Xb = Xg + (size_t)b * XSTR + (size_t)c * 128;
        const float2 w2 = *(const float2*)&cw[2 * c];
        const float2 h2 = *(const float2*)&cwh[2 * c];
        #pragma unroll
        for (int kb = 0; kb < 2; ++kb) {
            const bf16x8 xr = *(const bf16x8*)&Xb[kb * 32 + g4 * 8];
            const bf16x8 xi = *(const bf16x8*)&Xb[64 + kb * 32 + g4 * 8];
            float yr[8], yi[8];
            #pragma unroll
            for (int j = 0; j < 8; ++j) {
                const float m   = mask_s[kb * 32 + g4 * 8 + j];
                const float fre = fmaf(m, h2.x, w2.x);
                const float fim = fmaf(m, h2.y, w2.y);
                const float fxr = bf2f((unsigned short)xr[j]);
                const float fxi = bf2f((unsigned short)xi[j]);
                yr[j] = fxr * fre - fxi * fim;
                yi[j] = fxr * fim + fxi * fre;
            }
            unsigned ur[4], ui[4];
            #pragma unroll
            for (int jj = 0; jj < 4; ++jj) {
                ur[jj] = cvtpk(yr[2 * jj], yr[2 * jj + 1]);
                ui[jj] = cvtpk(yi[2 * jj], yi[2 * jj + 1]);
            }
            Yr[ct][kb] = *(bf16x8*)ur;
            Yi[ct][kb] = *(bf16x8*)ui;
        }
    }

    #pragma unroll
    for (int mt = 0; mt < 7; ++mt) {
        const int nr = mt * 16 + cc;
        f32x4v o[2];
        o[0] = o[1] = (f32x4v){0.f, 0.f, 0.f, 0.f};
        #pragma unroll
        for (int kb = 0; kb < 2; ++kb) {
            const int e0 = nr * 64 + kb * 32 + g4 * 8;
            const bf16x8 A0 = *(const bf16x8*)&imgI[e0];
            const bf16x8 A1 = *(const bf16x8*)&imgI[8192 + e0];
            #pragma unroll
            for (int ct = 0; ct < 2; ++ct) {
                o[ct] = __builtin_amdgcn_mfma_f32_16x16x32_bf16(A0, Yr[ct][kb], o[ct], 0, 0, 0);
                o[ct] = __builtin_amdgcn_mfma_f32_16x16x32_bf16(A1, Yi[ct][kb], o[ct], 0, 0, 0);
            }
        }
        #pragma unroll
        for (int ct = 0; ct < 2; ++ct) {
            const int c = wv * 32 + ct * 16 + cc;
            #pragma unroll
            for (int reg = 0; reg < 4; ++reg) {
                const int n = mt * 16 + g4 * 4 + reg;
                if (n < SEQ) {
                    const size_t idx = (size_t)n * BD + (size_t)b * DIM + c;
                    out[idx] = x[idx] + o[ct][reg];
                }
            }
        }
    }
}

// ---------------------------------------------------------------------------
extern "C" void kernel_launch(void* const* d_in, const int* in_sizes, int n_in,
                              void* d_out, int out_size, void* d_ws, size_t ws_size,
                              hipStream_t stream)
{
    (void)in_sizes; (void)n_in; (void)out_size; (void)ws_size;
    const float* x    = (const float*)d_in[0];
    const float* cw   = (const float*)d_in[1];
    const float* cwh  = (const float*)d_in[2];
    const float* thrp = (const float*)d_in[3];
    const float* gam  = (const float*)d_in[4];
    const float* bet  = (const float*)d_in[5];
    float* out = (float*)d_out;

    char* ws = (char*)d_ws;
    unsigned short* imgF = (unsigned short*)(ws);                    // 32768 B
    unsigned short* imgI = (unsigned short*)(ws + 32768);            // 32768 B
    unsigned short* Xg   = (unsigned short*)(ws + 65536);            // 67,108,864 B
    float* normE    = (float*)(ws + 65536 + 67108864);               // 417,792 B
    unsigned* hist  = (unsigned*)(ws + 65536 + 67108864 + 417792);   // 32768 B
    unsigned* done  = (unsigned*)(ws + 65536 + 67108864 + 417792 + 32768);       // 64 B
    unsigned* sel   = (unsigned*)(ws + 65536 + 67108864 + 417792 + 32768 + 64);  // 64 B
    float* thresh   = (float*)(ws + 65536 + 67108864 + 417792 + 32768 + 128);

    k_tables<<<64, 256, 0, stream>>>(imgF, imgI);
    (void)hipMemsetAsync(hist, 0, 32768 + 64, stream);   // hist + done (4 slots)

    // layer 0 fwd
    k_fwd<<<BATCH, 256, 0, stream>>>(x, gam, bet, imgF, Xg, normE);
    k_hist0<<<96, 256, 0, stream>>>(normE, hist);
    k_sel<<<96, 256, 0, stream>>>(normE, hist, sel, done, thrp, 0, 1, thresh);
    k_sel<<<96, 256, 0, stream>>>(normE, hist, sel, done, thrp, 0, 2, thresh);
    // layer 0 asb + layer 1 fwd (fused)
    k_asb_fwd<<<BATCH, 256, 0, stream>>>(x, cw, cwh, imgI, imgF,
                                         gam + DIM, bet + DIM,
                                         normE, thresh, out, Xg);
    k_hist0<<<96, 256, 0, stream>>>(normE, hist);
    k_sel<<<96, 256, 0, stream>>>(normE, hist, sel, done, thrp, 1, 1, thresh);
    k_sel<<<96, 256, 0, stream>>>(normE, hist, sel, done, thrp, 1, 2, thresh);
    // layer 1 asb (final)
    k_asb<<<BATCH, 256, 0, stream>>>(out, cw + DIM * 2, cwh + DIM * 2,
                                     Xg, imgI, normE, thresh, out);
}

// Round 13
// 367.892 us; speedup vs baseline: 1.4264x; 1.0869x over previous
//
#include <hip/hip_runtime.h>
#include <math.h>

#define SEQ    100
#define BATCH  2048
#define DIM    128
#define NF     51
#define NLAYER 2
#define MTOT   (BATCH * NF)
#define BD     (BATCH * DIM)
#define XSTR   16384   // ushorts per batch in Xg: [c(128)][plane(2)][k(64)]

typedef __attribute__((ext_vector_type(8))) short bf16x8;
typedef __attribute__((ext_vector_type(4))) float f32x4v;

__device__ __forceinline__ unsigned cvtpk(float lo, float hi) {
    unsigned r;
    asm("v_cvt_pk_bf16_f32 %0, %1, %2" : "=v"(r) : "v"(lo), "v"(hi));
    return r;
}
__device__ __forceinline__ unsigned short f2bf(float f) {
    unsigned u = __float_as_uint(f);
    return (unsigned short)((u + 0x7FFFu + ((u >> 16) & 1u)) >> 16);
}
__device__ __forceinline__ float bf2f(unsigned short u) {
    return __uint_as_float((unsigned)u << 16);
}

// ---------------------------------------------------------------- tables ---
// imgF [p][k(64)][n(128)] bf16: p0 = 0.1*cos(2pi k n/100), p1 = -0.1*sin; 0-pad.
// imgI [p][n(128)][k(64)] bf16: p0 = a_k*cos, p1 = -a_k*sin; a_k = 0.1/0.2.
__global__ void k_tables(unsigned short* __restrict__ imgF,
                         unsigned short* __restrict__ imgI) {
    const int i = blockIdx.x * 256 + threadIdx.x;   // 16384 per table
    const float W = 6.28318530717958647692f / 100.f;
    if (i < 2 * 64 * 128) {
        const int p = i >> 13, k = (i >> 7) & 63, n = i & 127;
        float v = 0.f;
        if (k < NF && n < SEQ) {
            float s, c; sincosf((float)((k * n) % 100) * W, &s, &c);
            v = 0.1f * (p ? -s : c);
        }
        imgF[i] = f2bf(v);
    }
    if (i < 2 * 128 * 64) {
        const int p = i >> 13, n = (i >> 6) & 127, k = i & 63;
        float v = 0.f;
        if (k < NF && n < SEQ) {
            float s, c; sincosf((float)((k * n) % 100) * W, &s, &c);
            const float a = (k == 0 || k == 50) ? 0.1f : 0.2f;
            v = p ? -a * s : a * c;
        }
        imgI[i] = f2bf(v);
    }
}

// ------------------- A: LN + fwd DFT + X store (bf16) + energy + normE -----
// R6-proven structure: 34 KB LDS, (256,4), single hoisted x fetch.
__global__ __launch_bounds__(256, 4) void k_fwd(
    const float* __restrict__ x,
    const float* __restrict__ gamma, const float* __restrict__ beta,
    const unsigned short* __restrict__ imgF,
    unsigned short* __restrict__ Xg,   // [BATCH][c][plane][k64] bf16
    float* __restrict__ normE)
{
    __shared__ __align__(16) unsigned short hT[128 * 128];   // 32 KB
    __shared__ float epart[64][4];
    __shared__ float energy_s[64];
    __shared__ float med_s;

    const int b = blockIdx.x, t = threadIdx.x;
    const int lane = t & 63, wv = t >> 6, g4 = lane >> 4, cc = lane & 15;

    // ---- fused LN + h^T staging (single x fetch; loads hoisted) ----
    {
        const int c0 = lane * 2;
        const float2 gv = *(const float2*)&gamma[c0];
        const float2 bv = *(const float2*)&beta[c0];
        float2 v[4][8];
        #pragma unroll
        for (int slot = 0; slot < 4; ++slot) {
            const int n0 = (slot * 4 + wv) * 8;
            #pragma unroll
            for (int j = 0; j < 8; ++j)
                if (n0 + j < SEQ)
                    v[slot][j] = *(const float2*)&x[(size_t)(n0 + j) * BD + (size_t)b * DIM + c0];
        }
        #pragma unroll
        for (int slot = 0; slot < 4; ++slot) {
            const int chunk = slot * 4 + wv;       // 0..15
            const int n0 = chunk * 8;
            float he[8], ho[8];
            #pragma unroll
            for (int j = 0; j < 8; ++j) {
                he[j] = 0.f; ho[j] = 0.f;
                if (n0 + j < SEQ) {
                    float s  = v[slot][j].x + v[slot][j].y;
                    float s2 = fmaf(v[slot][j].x, v[slot][j].x, v[slot][j].y * v[slot][j].y);
                    #pragma unroll
                    for (int off = 1; off < 64; off <<= 1) {
                        s  += __shfl_xor(s,  off, 64);
                        s2 += __shfl_xor(s2, off, 64);
                    }
                    const float mu   = s * (1.f / 128.f);
                    const float rstd = rsqrtf(s2 * (1.f / 128.f) - mu * mu + 1e-5f);
                    he[j] = fmaf((v[slot][j].x - mu) * rstd, gv.x, bv.x);
                    ho[j] = fmaf((v[slot][j].y - mu) * rstd, gv.y, bv.y);
                }
            }
            int4 ve, vo;
            ve.x = (int)cvtpk(he[0], he[1]); ve.y = (int)cvtpk(he[2], he[3]);
            ve.z = (int)cvtpk(he[4], he[5]); ve.w = (int)cvtpk(he[6], he[7]);
            vo.x = (int)cvtpk(ho[0], ho[1]); vo.y = (int)cvtpk(ho[2], ho[3]);
            vo.z = (int)cvtpk(ho[4], ho[5]); vo.w = (int)cvtpk(ho[6], ho[7]);
            const int sw = (chunk ^ (lane & 7)) << 3;   // swizzle f(c)=(c>>1)&7
            *(int4*)&hT[(c0    ) * 128 + sw] = ve;
            *(int4*)&hT[(c0 + 1) * 128 + sw] = vo;
        }
    }
    __syncthreads();

    // B-fragments: wave's 2 c-tiles
    bf16x8 Bf[2][4];
    #pragma unroll
    for (int ct = 0; ct < 2; ++ct) {
        const int c = wv * 32 + ct * 16 + cc;
        #pragma unroll
        for (int ks = 0; ks < 4; ++ks)
            Bf[ct][ks] = *(const bf16x8*)&hT[c * 128 + (((ks * 4 + g4) ^ (cc >> 1)) << 3)];
    }

    #pragma unroll
    for (int mt = 0; mt < 4; ++mt) {
        const int kr = mt * 16 + cc;
        f32x4v aR[2], aI[2];
        aR[0] = aR[1] = aI[0] = aI[1] = (f32x4v){0.f, 0.f, 0.f, 0.f};
        #pragma unroll
        for (int ks = 0; ks < 4; ++ks) {
            const int e0 = kr * 128 + ks * 32 + g4 * 8;
            const bf16x8 A0 = *(const bf16x8*)&imgF[e0];
            const bf16x8 A1 = *(const bf16x8*)&imgF[8192 + e0];
            #pragma unroll
            for (int ct = 0; ct < 2; ++ct) {
                aR[ct] = __builtin_amdgcn_mfma_f32_16x16x32_bf16(A0, Bf[ct][ks], aR[ct], 0, 0, 0);
                aI[ct] = __builtin_amdgcn_mfma_f32_16x16x32_bf16(A1, Bf[ct][ks], aI[ct], 0, 0, 0);
            }
        }
        // energy partials (f32, before bf16 rounding)
        #pragma unroll
        for (int reg = 0; reg < 4; ++reg) {
            float e = aR[0][reg] * aR[0][reg] + aI[0][reg] * aI[0][reg]
                    + aR[1][reg] * aR[1][reg] + aI[1][reg] * aI[1][reg];
            e += __shfl_xor(e, 1, 64); e += __shfl_xor(e, 2, 64);
            e += __shfl_xor(e, 4, 64); e += __shfl_xor(e, 8, 64);
            if (cc == 0) epart[mt * 16 + g4 * 4 + reg][wv] = e;
        }
        // X store: acc (k=mt*16+g4*4+reg, c) -> Xg[b][c][plane][k] packed bf16
        #pragma unroll
        for (int ct = 0; ct < 2; ++ct) {
            const int c = wv * 32 + ct * 16 + cc;
            unsigned short* Xb = Xg + (size_t)b * XSTR + (size_t)c * 128;
            const int k0 = mt * 16 + g4 * 4;
            uint2 pr, pi;
            pr.x = cvtpk(aR[ct][0], aR[ct][1]); pr.y = cvtpk(aR[ct][2], aR[ct][3]);
            pi.x = cvtpk(aI[ct][0], aI[ct][1]); pi.y = cvtpk(aI[ct][2], aI[ct][3]);
            *(uint2*)&Xb[k0]      = pr;   // plane 0 (Re)
            *(uint2*)&Xb[64 + k0] = pi;   // plane 1 (Im)
        }
    }
    __syncthreads();
    if (t < 64) energy_s[t] = epart[t][0] + epart[t][1] + epart[t][2] + epart[t][3];
    __syncthreads();
    if (t < NF) {
        const float e = energy_s[t];
        int cnt = 0;
        for (int j = 0; j < NF; ++j) {
            const float ej = energy_s[j];
            cnt += (ej < e || (ej == e && j < t)) ? 1 : 0;
        }
        if (cnt == (NF - 1) / 2) med_s = e;
    }
    __syncthreads();
    if (t < NF) normE[b * NF + t] = energy_s[t] / (med_s + 1e-6f);
}

// ----------------------- radix round 0: LDS-aggregated histogram ----------
__global__ void k_hist0(const float* __restrict__ normE,
                        unsigned* __restrict__ hist)
{
    __shared__ unsigned lh[2048];
    for (int i = threadIdx.x; i < 2048; i += 256) lh[i] = 0;
    __syncthreads();
    for (int i = blockIdx.x * 256 + threadIdx.x; i < MTOT; i += gridDim.x * 256)
        atomicAdd(&lh[__float_as_uint(normE[i]) >> 21], 1u);
    __syncthreads();
    for (int i = threadIdx.x; i < 2048; i += 256) {
        const unsigned c = lh[i];
        if (c) atomicAdd(&hist[i], c);
    }
}

// --------------------------- radix select rounds 1 & 2 (fused hist+scan) ---
// hist layout (u32): [0,2048) round0 | [2048,6144) round1 (2 ranks) |
//                    [6144,8192) round2 (2 ranks). done: slot per (layer,phase).
__global__ void k_sel(const float* __restrict__ normE,
                      unsigned* __restrict__ hist,
                      unsigned* __restrict__ sel,
                      unsigned* __restrict__ done,
                      const float* __restrict__ thrp,
                      const int layer, const int phase,
                      float* __restrict__ thresh)
{
    __shared__ unsigned lh[4096];
    __shared__ unsigned sp[2], sc[2];
    __shared__ unsigned ticket_s;
    __shared__ float vb[2];
    const int t = threadIdx.x;
    const float q = thrp[layer] * (float)(MTOT - 1);
    const unsigned r0 = (unsigned)floorf(q);

    if (phase == 1) {
        // entry scan of round-0 hist (2048 bins, shift 21, prefix 0)
        if (t < 128) {
            const int j = t >> 6, ln = t & 63;
            const unsigned rk = r0 + (unsigned)j;
            unsigned sum = 0;
            for (int i = 0; i < 32; ++i) sum += hist[ln * 32 + i];
            unsigned pre = sum;
            #pragma unroll
            for (int off = 1; off < 64; off <<= 1) {
                const unsigned tt = __shfl_up(pre, off, 64);
                if (ln >= off) pre += tt;
            }
            const unsigned excl = pre - sum;
            if (rk >= excl && rk < excl + sum) {
                unsigned cum = excl;
                for (int i = 0; i < 32; ++i) {
                    const unsigned hc = hist[ln * 32 + i];
                    if (rk < cum + hc) { sp[j] = (unsigned)(ln * 32 + i) << 21; sc[j] = cum; break; }
                    cum += hc;
                }
            }
        }
    } else {
        if (t < 2) { sp[t] = sel[2 * t]; sc[t] = sel[2 * t + 1]; }
    }
    __syncthreads();
    const unsigned p0 = sp[0], p1 = sp[1];
    const int bins      = (phase == 1) ? 2048 : 1024;
    const int shift     = (phase == 1) ? 10 : 0;
    const unsigned hmsk = (phase == 1) ? 0xFFE00000u : 0xFFFFFC00u;
    const int region    = (phase == 1) ? 2048 : 6144;

    for (int i = t; i < 2 * bins; i += 256) lh[i] = 0;
    __syncthreads();
    for (int i = blockIdx.x * 256 + t; i < MTOT; i += gridDim.x * 256) {
        const unsigned v = __float_as_uint(normE[i]);
        const unsigned bin = (v >> shift) & (unsigned)(bins - 1);
        if ((v & hmsk) == p0) atomicAdd(&lh[bin], 1u);
        if ((v & hmsk) == p1) atomicAdd(&lh[bins + bin], 1u);
    }
    __syncthreads();
    for (int i = t; i < 2 * bins; i += 256) {
        const unsigned c = lh[i];
        if (c) atomicAdd(&hist[region + i], c);
    }
    __threadfence();
    if (t == 0) ticket_s = atomicAdd(&done[(layer << 1) + (phase - 1)], 1u);
    __syncthreads();
    if (ticket_s != (unsigned)(gridDim.x - 1)) return;
    __threadfence();

    // last block: scan both ranks of this round
    if (t < 128) {
        const int j = t >> 6, ln = t & 63;
        const unsigned rk  = r0 + (unsigned)j;
        const unsigned rem = rk - sc[j];
        const unsigned* H  = hist + region + j * bins;
        const int per = bins / 64;
        unsigned sum = 0;
        for (int i = 0; i < per; ++i)
            sum += __hip_atomic_load(&H[ln * per + i], __ATOMIC_RELAXED, __HIP_MEMORY_SCOPE_AGENT);
        unsigned pre = sum;
        #pragma unroll
        for (int off = 1; off < 64; off <<= 1) {
            const unsigned tt = __shfl_up(pre, off, 64);
            if (ln >= off) pre += tt;
        }
        const unsigned excl = pre - sum;
        if (rem >= excl && rem < excl + sum) {
            unsigned cum = excl;
            for (int i = 0; i < per; ++i) {
                const unsigned hc = __hip_atomic_load(&H[ln * per + i],
                                        __ATOMIC_RELAXED, __HIP_MEMORY_SCOPE_AGENT);
                if (rem < cum + hc) {
                    const unsigned bin = (unsigned)(ln * per + i);
                    if (phase == 1) { sel[2 * j] = sp[j] | (bin << 10); sel[2 * j + 1] = sc[j] + cum; }
                    else            vb[j] = __uint_as_float(sp[j] | bin);
                    break;
                }
                cum += hc;
            }
        }
    }
    __syncthreads();
    if (phase == 1) { for (int i = t; i < 6144; i += 256) hist[i] = 0u; }
    else            { for (int i = t; i < 2048; i += 256) hist[6144 + i] = 0u; }
    if (t == 0 && phase == 2) {
        const float frac = q - floorf(q);
        thresh[0] = vb[0] * (1.f - frac) + vb[1] * frac;
    }
}

// ===== C-fused: irfft+residual (layer l) THEN LN+fwd DFT (layer l+1) =======
// Spill-fix vs R12: `out` tile retained as PACKED BF16 (ovp, 28 u32 regs
// instead of 56 f32); LN partial sums computed inline in phase 2 from the
// still-live f32 values (stats exact); phase 4 unpacks bf16 for h staging.
__global__ __launch_bounds__(256, 4) void k_asb_fwd(
    const float* __restrict__ x,
    const float* __restrict__ cw, const float* __restrict__ cwh,
    const unsigned short* __restrict__ imgI,
    const unsigned short* __restrict__ imgF,
    const float* __restrict__ gamma_n, const float* __restrict__ beta_n,
    float* __restrict__ normE,          // read (layer l mask) AND written (layer l+1)
    const float* __restrict__ thresh,
    float* __restrict__ out,
    unsigned short* __restrict__ Xg)
{
    __shared__ __align__(16) unsigned short hT[128 * 128];   // 32 KB
    __shared__ float mask_s[64];
    __shared__ float part_s[112][4], part_q[112][4];
    __shared__ float2 musv[112];

    const int b = blockIdx.x, t = threadIdx.x;
    const int lane = t & 63, wv = t >> 6, g4 = lane >> 4, cc = lane & 15;

    if (t < 64) mask_s[t] = (t < NF && normE[b * NF + t] < thresh[0]) ? 1.f : 0.f;
    __syncthreads();

    // ---- phase 1: load X, weight, build inverse B-frags ----
    bf16x8 Yr[2][2], Yi[2][2];
    float gn[2], bn[2];
    #pragma unroll
    for (int ct = 0; ct < 2; ++ct) {
        const int c = wv * 32 + ct * 16 + cc;
        gn[ct] = gamma_n[c]; bn[ct] = beta_n[c];
        const unsigned short* Xb = Xg + (size_t)b * XSTR + (size_t)c * 128;
        const float2 w2 = *(const float2*)&cw[2 * c];
        const float2 h2 = *(const float2*)&cwh[2 * c];
        #pragma unroll
        for (int kb = 0; kb < 2; ++kb) {
            const bf16x8 xr = *(const bf16x8*)&Xb[kb * 32 + g4 * 8];
            const bf16x8 xi = *(const bf16x8*)&Xb[64 + kb * 32 + g4 * 8];
            float yr[8], yi[8];
            #pragma unroll
            for (int j = 0; j < 8; ++j) {
                const float m   = mask_s[kb * 32 + g4 * 8 + j];
                const float fre = fmaf(m, h2.x, w2.x);
                const float fim = fmaf(m, h2.y, w2.y);
                const float fxr = bf2f((unsigned short)xr[j]);
                const float fxi = bf2f((unsigned short)xi[j]);
                yr[j] = fxr * fre - fxi * fim;
                yi[j] = fxr * fim + fxi * fre;
            }
            unsigned ur[4], ui[4];
            #pragma unroll
            for (int jj = 0; jj < 4; ++jj) {
                ur[jj] = cvtpk(yr[2 * jj], yr[2 * jj + 1]);
                ui[jj] = cvtpk(yi[2 * jj], yi[2 * jj + 1]);
            }
            Yr[ct][kb] = *(bf16x8*)ur;
            Yi[ct][kb] = *(bf16x8*)ui;
        }
    }

    // ---- phase 2: inverse DFT + residual + store; retain out as bf16 pairs;
    //              LN partial sums computed inline from f32 values ----
    unsigned ovp[7][2][2];   // [mt][ct][pair] bf16x2, pair 0 = regs{0,1}, 1 = regs{2,3}
    #pragma unroll
    for (int mt = 0; mt < 7; ++mt) {
        const int nr = mt * 16 + cc;
        f32x4v o[2];
        o[0] = o[1] = (f32x4v){0.f, 0.f, 0.f, 0.f};
        #pragma unroll
        for (int kb = 0; kb < 2; ++kb) {
            const int e0 = nr * 64 + kb * 32 + g4 * 8;
            const bf16x8 A0 = *(const bf16x8*)&imgI[e0];
            const bf16x8 A1 = *(const bf16x8*)&imgI[8192 + e0];
            #pragma unroll
            for (int ct = 0; ct < 2; ++ct) {
                o[ct] = __builtin_amdgcn_mfma_f32_16x16x32_bf16(A0, Yr[ct][kb], o[ct], 0, 0, 0);
                o[ct] = __builtin_amdgcn_mfma_f32_16x16x32_bf16(A1, Yi[ct][kb], o[ct], 0, 0, 0);
            }
        }
        float vals[2][4];
        #pragma unroll
        for (int ct = 0; ct < 2; ++ct) {
            const int c = wv * 32 + ct * 16 + cc;
            #pragma unroll
            for (int reg = 0; reg < 4; ++reg) {
                const int n = mt * 16 + g4 * 4 + reg;
                float val = 0.f;
                if (n < SEQ) {
                    const size_t idx = (size_t)n * BD + (size_t)b * DIM + c;
                    val = x[idx] + o[ct][reg];
                    out[idx] = val;
                }
                vals[ct][reg] = val;
            }
            ovp[mt][ct][0] = cvtpk(vals[ct][0], vals[ct][1]);
            ovp[mt][ct][1] = cvtpk(vals[ct][2], vals[ct][3]);
        }
        // LN partials for this mt's 4 rows (sum over the 2 ct + 16 cc lanes)
        #pragma unroll
        for (int reg = 0; reg < 4; ++reg) {
            float s  = vals[0][reg] + vals[1][reg];
            float s2 = fmaf(vals[0][reg], vals[0][reg], vals[1][reg] * vals[1][reg]);
            s  += __shfl_xor(s, 1, 64);  s  += __shfl_xor(s, 2, 64);
            s  += __shfl_xor(s, 4, 64);  s  += __shfl_xor(s, 8, 64);
            s2 += __shfl_xor(s2, 1, 64); s2 += __shfl_xor(s2, 2, 64);
            s2 += __shfl_xor(s2, 4, 64); s2 += __shfl_xor(s2, 8, 64);
            if (cc == 0) {
                const int n = mt * 16 + g4 * 4 + reg;
                part_s[n][wv] = s; part_q[n][wv] = s2;
            }
        }
    }
    __syncthreads();
    if (t < 112) {
        const float s  = part_s[t][0] + part_s[t][1] + part_s[t][2] + part_s[t][3];
        const float sq = part_q[t][0] + part_q[t][1] + part_q[t][2] + part_q[t][3];
        const float mu = s * (1.f / 128.f);
        const float rstd = rsqrtf(sq * (1.f / 128.f) - mu * mu + 1e-5f);
        musv[t] = make_float2(mu, rstd);
    }
    __syncthreads();

    // ---- phase 4: stage bf16 LN(out) into hT (+ zero-fill n in [112,128)) --
    {
        const int cf = t >> 1, chf = 14 + (t & 1);
        *(int4*)&hT[cf * 128 + ((chf ^ ((cf >> 1) & 7)) << 3)] = (int4){0, 0, 0, 0};
    }
    #pragma unroll
    for (int mt = 0; mt < 7; ++mt) {
        #pragma unroll
        for (int ct = 0; ct < 2; ++ct) {
            const int c = wv * 32 + ct * 16 + cc;
            #pragma unroll
            for (int pr = 0; pr < 2; ++pr) {
                const int n0 = mt * 16 + g4 * 4 + pr * 2;
                const unsigned pv = ovp[mt][ct][pr];
                float h0 = 0.f, h1 = 0.f;
                if (n0 < SEQ) {
                    const float2 ms = musv[n0];
                    const float v0 = bf2f((unsigned short)(pv & 0xFFFFu));
                    h0 = fmaf((v0 - ms.x) * ms.y, gn[ct], bn[ct]);
                }
                if (n0 + 1 < SEQ) {
                    const float2 ms = musv[n0 + 1];
                    const float v1 = bf2f((unsigned short)(pv >> 16));
                    h1 = fmaf((v1 - ms.x) * ms.y, gn[ct], bn[ct]);
                }
                const unsigned u = cvtpk(h0, h1);
                const int e = c * 128 + (((n0 >> 3) ^ ((c >> 1) & 7)) << 3) + (n0 & 7);
                *(unsigned*)&hT[e] = u;
            }
        }
    }
    __syncthreads();

    // ---- phase 5: fwd DFT + energy + median + normE (hT-union tail) ----
    {
        bf16x8 Bf[2][4];
        #pragma unroll
        for (int ct = 0; ct < 2; ++ct) {
            const int c = wv * 32 + ct * 16 + cc;
            #pragma unroll
            for (int ks = 0; ks < 4; ++ks)
                Bf[ct][ks] = *(const bf16x8*)&hT[c * 128 + (((ks * 4 + g4) ^ (cc >> 1)) << 3)];
        }
        __syncthreads();   // hT dead -> reuse front as f32 scratch

        float* epart    = (float*)hT;          // [64][4]
        float* energy_s = (float*)hT + 256;    // [64]
        float* medp     = (float*)hT + 320;    // [1]

        #pragma unroll
        for (int mt = 0; mt < 4; ++mt) {
            const int kr = mt * 16 + cc;
            f32x4v aR[2], aI[2];
            aR[0] = aR[1] = aI[0] = aI[1] = (f32x4v){0.f, 0.f, 0.f, 0.f};
            #pragma unroll
            for (int ks = 0; ks < 4; ++ks) {
                const int e0 = kr * 128 + ks * 32 + g4 * 8;
                const bf16x8 A0 = *(const bf16x8*)&imgF[e0];
                const bf16x8 A1 = *(const bf16x8*)&imgF[8192 + e0];
                #pragma unroll
                for (int ct = 0; ct < 2; ++ct) {
                    aR[ct] = __builtin_amdgcn_mfma_f32_16x16x32_bf16(A0, Bf[ct][ks], aR[ct], 0, 0, 0);
                    aI[ct] = __builtin_amdgcn_mfma_f32_16x16x32_bf16(A1, Bf[ct][ks], aI[ct], 0, 0, 0);
                }
            }
            #pragma unroll
            for (int reg = 0; reg < 4; ++reg) {
                float e = aR[0][reg] * aR[0][reg] + aI[0][reg] * aI[0][reg]
                        + aR[1][reg] * aR[1][reg] + aI[1][reg] * aI[1][reg];
                e += __shfl_xor(e, 1, 64); e += __shfl_xor(e, 2, 64);
                e += __shfl_xor(e, 4, 64); e += __shfl_xor(e, 8, 64);
                if (cc == 0) epart[(mt * 16 + g4 * 4 + reg) * 4 + wv] = e;
            }
            #pragma unroll
            for (int ct = 0; ct < 2; ++ct) {
                const int c = wv * 32 + ct * 16 + cc;
                unsigned short* Xb = Xg + (size_t)b * XSTR + (size_t)c * 128;
                const int k0 = mt * 16 + g4 * 4;
                uint2 pr, pi;
                pr.x = cvtpk(aR[ct][0], aR[ct][1]); pr.y = cvtpk(aR[ct][2], aR[ct][3]);
                pi.x = cvtpk(aI[ct][0], aI[ct][1]); pi.y = cvtpk(aI[ct][2], aI[ct][3]);
                *(uint2*)&Xb[k0]      = pr;
                *(uint2*)&Xb[64 + k0] = pi;
            }
        }
        __syncthreads();
        if (t < 64) energy_s[t] = epart[4 * t] + epart[4 * t + 1]
                                + epart[4 * t + 2] + epart[4 * t + 3];
        __syncthreads();
        if (t < NF) {
            const float e = energy_s[t];
            int cnt = 0;
            for (int j = 0; j < NF; ++j) {
                const float ej = energy_s[j];
                cnt += (ej < e || (ej == e && j < t)) ? 1 : 0;
            }
            if (cnt == (NF - 1) / 2) *medp = e;
        }
        __syncthreads();
        if (t < NF) normE[b * NF + t] = energy_s[t] / (*medp + 1e-6f);
    }
}

// --------------- C-final: load X + weight + irfft + residual ---------------
__global__ __launch_bounds__(256, 4) void k_asb(
    const float* __restrict__ x,
    const float* __restrict__ cw, const float* __restrict__ cwh,
    const unsigned short* __restrict__ Xg,
    const unsigned short* __restrict__ imgI,
    const float* __restrict__ normE, const float* __restrict__ thresh,
    float* __restrict__ out)
{
    __shared__ __align__(16) float mask_s[64];

    const int b = blockIdx.x, t = threadIdx.x;
    const int lane = t & 63, wv = t >> 6, g4 = lane >> 4, cc = lane & 15;

    if (t < 64) mask_s[t] = (t < NF && normE[b * NF + t] < thresh[0]) ? 1.f : 0.f;
    __syncthreads();

    bf16x8 Yr[2][2], Yi[2][2];
    #pragma unroll
    for (int ct = 0; ct < 2; ++ct) {
        const int c = wv * 32 + ct * 16 + cc;
        const unsigned short* Xb = Xg + (size_t)b * XSTR + (size_t)c * 128;
        const float2 w2 = *(const float2*)&cw[2 * c];
        const float2 h2 = *(const float2*)&cwh[2 * c];
        #pragma unroll
        for (int kb = 0; kb < 2; ++kb) {
            const bf16x8 xr = *(const bf16x8*)&Xb[kb * 32 + g4 * 8];
            const bf16x8 xi = *(const bf16x8*)&Xb[64 + kb * 32 + g4 * 8];
            float yr[8], yi[8];
            #pragma unroll
            for (int j = 0; j < 8; ++j) {
                const float m   = mask_s[kb * 32 + g4 * 8 + j];
                const float fre = fmaf(m, h2.x, w2.x);
                const float fim = fmaf(m, h2.y, w2.y);
                const float fxr = bf2f((unsigned short)xr[j]);
                const float fxi = bf2f((unsigned short)xi[j]);
                yr[j] = fxr * fre - fxi * fim;
                yi[j] = fxr * fim + fxi * fre;
            }
            unsigned ur[4], ui[4];
            #pragma unroll
            for (int jj = 0; jj < 4; ++jj) {
                ur[jj] = cvtpk(yr[2 * jj], yr[2 * jj + 1]);
                ui[jj] = cvtpk(yi[2 * jj], yi[2 * jj + 1]);
            }
            Yr[ct][kb] = *(bf16x8*)ur;
            Yi[ct][kb] = *(bf16x8*)ui;
        }
    }

    #pragma unroll
    for (int mt = 0; mt < 7; ++mt) {
        const int nr = mt * 16 + cc;
        f32x4v o[2];
        o[0] = o[1] = (f32x4v){0.f, 0.f, 0.f, 0.f};
        #pragma unroll
        for (int kb = 0; kb < 2; ++kb) {
            const int e0 = nr * 64 + kb * 32 + g4 * 8;
            const bf16x8 A0 = *(const bf16x8*)&imgI[e0];
            const bf16x8 A1 = *(const bf16x8*)&imgI[8192 + e0];
            #pragma unroll
            for (int ct = 0; ct < 2; ++ct) {
                o[ct] = __builtin_amdgcn_mfma_f32_16x16x32_bf16(A0, Yr[ct][kb], o[ct], 0, 0, 0);
                o[ct] = __builtin_amdgcn_mfma_f32_16x16x32_bf16(A1, Yi[ct][kb], o[ct], 0, 0, 0);
            }
        }
        #pragma unroll
        for (int ct = 0; ct < 2; ++ct) {
            const int c = wv * 32 + ct * 16 + cc;
            #pragma unroll
            for (int reg = 0; reg < 4; ++reg) {
                const int n = mt * 16 + g4 * 4 + reg;
                if (n < SEQ) {
                    const size_t idx = (size_t)n * BD + (size_t)b * DIM + c;
                    out[idx] = x[idx] + o[ct][reg];
                }
            }
        }
    }
}

// ---------------------------------------------------------------------------
extern "C" void kernel_launch(void* const* d_in, const int* in_sizes, int n_in,
                              void* d_out, int out_size, void* d_ws, size_t ws_size,
                              hipStream_t stream)
{
    (void)in_sizes; (void)n_in; (void)out_size; (void)ws_size;
    const float* x    = (const float*)d_in[0];
    const float* cw   = (const float*)d_in[1];
    const float* cwh  = (const float*)d_in[2];
    const float* thrp = (const float*)d_in[3];
    const float* gam  = (const float*)d_in[4];
    const float* bet  = (const float*)d_in[5];
    float* out = (float*)d_out;

    char* ws = (char*)d_ws;
    unsigned short* imgF = (unsigned short*)(ws);                    // 32768 B
    unsigned short* imgI = (unsigned short*)(ws + 32768);            // 32768 B
    unsigned short* Xg   = (unsigned short*)(ws + 65536);            // 67,108,864 B
    float* normE    = (float*)(ws + 65536 + 67108864);               // 417,792 B
    unsigned* hist  = (unsigned*)(ws + 65536 + 67108864 + 417792);   // 32768 B
    unsigned* done  = (unsigned*)(ws + 65536 + 67108864 + 417792 + 32768);       // 64 B
    unsigned* sel   = (unsigned*)(ws + 65536 + 67108864 + 417792 + 32768 + 64);  // 64 B
    float* thresh   = (float*)(ws + 65536 + 67108864 + 417792 + 32768 + 128);

    k_tables<<<64, 256, 0, stream>>>(imgF, imgI);
    (void)hipMemsetAsync(hist, 0, 32768 + 64, stream);   // hist + done (4 slots)

    // layer 0 fwd
    k_fwd<<<BATCH, 256, 0, stream>>>(x, gam, bet, imgF, Xg, normE);
    k_hist0<<<96, 256, 0, stream>>>(normE, hist);
    k_sel<<<96, 256, 0, stream>>>(normE, hist, sel, done, thrp, 0, 1, thresh);
    k_sel<<<96, 256, 0, stream>>>(normE, hist, sel, done, thrp, 0, 2, thresh);
    // layer 0 asb + layer 1 fwd (fused, spill-free)
    k_asb_fwd<<<BATCH, 256, 0, stream>>>(x, cw, cwh, imgI, imgF,
                                         gam + DIM, bet + DIM,
                                         normE, thresh, out, Xg);
    k_hist0<<<96, 256, 0, stream>>>(normE, hist);
    k_sel<<<96, 256, 0, stream>>>(normE, hist, sel, done, thrp, 1, 1, thresh);
    k_sel<<<96, 256, 0, stream>>>(normE, hist, sel, done, thrp, 1, 2, thresh);
    // layer 1 asb (final)
    k_asb<<<BATCH, 256, 0, stream>>>(out, cw + DIM * 2, cwh + DIM * 2,
                                     Xg, imgI, normE, thresh, out);
}

// Round 14
// 356.426 us; speedup vs baseline: 1.4723x; 1.0322x over previous
//
#include <hip/hip_runtime.h>
#include <math.h>

#define SEQ    100
#define BATCH  2048
#define DIM    128
#define NF     51
#define NLAYER 2
#define MTOT   (BATCH * NF)
#define BD     (BATCH * DIM)
#define XSTR   16384   // ushorts per batch in Xg: [c(128)][plane(2)][k(64)]

typedef __attribute__((ext_vector_type(8))) short bf16x8;
typedef __attribute__((ext_vector_type(4))) float f32x4v;

__device__ __forceinline__ unsigned cvtpk(float lo, float hi) {
    unsigned r;
    asm("v_cvt_pk_bf16_f32 %0, %1, %2" : "=v"(r) : "v"(lo), "v"(hi));
    return r;
}
__device__ __forceinline__ unsigned short f2bf(float f) {
    unsigned u = __float_as_uint(f);
    return (unsigned short)((u + 0x7FFFu + ((u >> 16) & 1u)) >> 16);
}
__device__ __forceinline__ float bf2f(unsigned short u) {
    return __uint_as_float((unsigned)u << 16);
}

// ---------------------------------------------------------------- tables ---
// imgF [p][k(64)][n(128)] bf16: p0 = 0.1*cos(2pi k n/100), p1 = -0.1*sin; 0-pad.
// imgI [p][n(128)][k(64)] bf16: p0 = a_k*cos, p1 = -a_k*sin; a_k = 0.1/0.2.
__global__ void k_tables(unsigned short* __restrict__ imgF,
                         unsigned short* __restrict__ imgI) {
    const int i = blockIdx.x * 256 + threadIdx.x;   // 16384 per table
    const float W = 6.28318530717958647692f / 100.f;
    if (i < 2 * 64 * 128) {
        const int p = i >> 13, k = (i >> 7) & 63, n = i & 127;
        float v = 0.f;
        if (k < NF && n < SEQ) {
            float s, c; sincosf((float)((k * n) % 100) * W, &s, &c);
            v = 0.1f * (p ? -s : c);
        }
        imgF[i] = f2bf(v);
    }
    if (i < 2 * 128 * 64) {
        const int p = i >> 13, n = (i >> 6) & 127, k = i & 63;
        float v = 0.f;
        if (k < NF && n < SEQ) {
            float s, c; sincosf((float)((k * n) % 100) * W, &s, &c);
            const float a = (k == 0 || k == 50) ? 0.1f : 0.2f;
            v = p ? -a * s : a * c;
        }
        imgI[i] = f2bf(v);
    }
}

// ------------------- A: LN + fwd DFT + X store (bf16) + energy + normE -----
// R6-proven structure: 34 KB LDS, (256,4), single hoisted x fetch.
__global__ __launch_bounds__(256, 4) void k_fwd(
    const float* __restrict__ x,
    const float* __restrict__ gamma, const float* __restrict__ beta,
    const unsigned short* __restrict__ imgF,
    unsigned short* __restrict__ Xg,   // [BATCH][c][plane][k64] bf16
    float* __restrict__ normE)
{
    __shared__ __align__(16) unsigned short hT[128 * 128];   // 32 KB
    __shared__ float epart[64][4];
    __shared__ float energy_s[64];
    __shared__ float med_s;

    const int b = blockIdx.x, t = threadIdx.x;
    const int lane = t & 63, wv = t >> 6, g4 = lane >> 4, cc = lane & 15;

    // ---- fused LN + h^T staging (single x fetch; loads hoisted) ----
    {
        const int c0 = lane * 2;
        const float2 gv = *(const float2*)&gamma[c0];
        const float2 bv = *(const float2*)&beta[c0];
        float2 v[4][8];
        #pragma unroll
        for (int slot = 0; slot < 4; ++slot) {
            const int n0 = (slot * 4 + wv) * 8;
            #pragma unroll
            for (int j = 0; j < 8; ++j)
                if (n0 + j < SEQ)
                    v[slot][j] = *(const float2*)&x[(size_t)(n0 + j) * BD + (size_t)b * DIM + c0];
        }
        #pragma unroll
        for (int slot = 0; slot < 4; ++slot) {
            const int chunk = slot * 4 + wv;       // 0..15
            const int n0 = chunk * 8;
            float he[8], ho[8];
            #pragma unroll
            for (int j = 0; j < 8; ++j) {
                he[j] = 0.f; ho[j] = 0.f;
                if (n0 + j < SEQ) {
                    float s  = v[slot][j].x + v[slot][j].y;
                    float s2 = fmaf(v[slot][j].x, v[slot][j].x, v[slot][j].y * v[slot][j].y);
                    #pragma unroll
                    for (int off = 1; off < 64; off <<= 1) {
                        s  += __shfl_xor(s,  off, 64);
                        s2 += __shfl_xor(s2, off, 64);
                    }
                    const float mu   = s * (1.f / 128.f);
                    const float rstd = rsqrtf(s2 * (1.f / 128.f) - mu * mu + 1e-5f);
                    he[j] = fmaf((v[slot][j].x - mu) * rstd, gv.x, bv.x);
                    ho[j] = fmaf((v[slot][j].y - mu) * rstd, gv.y, bv.y);
                }
            }
            int4 ve, vo;
            ve.x = (int)cvtpk(he[0], he[1]); ve.y = (int)cvtpk(he[2], he[3]);
            ve.z = (int)cvtpk(he[4], he[5]); ve.w = (int)cvtpk(he[6], he[7]);
            vo.x = (int)cvtpk(ho[0], ho[1]); vo.y = (int)cvtpk(ho[2], ho[3]);
            vo.z = (int)cvtpk(ho[4], ho[5]); vo.w = (int)cvtpk(ho[6], ho[7]);
            const int sw = (chunk ^ (lane & 7)) << 3;   // swizzle f(c)=(c>>1)&7
            *(int4*)&hT[(c0    ) * 128 + sw] = ve;
            *(int4*)&hT[(c0 + 1) * 128 + sw] = vo;
        }
    }
    __syncthreads();

    // B-fragments: wave's 2 c-tiles
    bf16x8 Bf[2][4];
    #pragma unroll
    for (int ct = 0; ct < 2; ++ct) {
        const int c = wv * 32 + ct * 16 + cc;
        #pragma unroll
        for (int ks = 0; ks < 4; ++ks)
            Bf[ct][ks] = *(const bf16x8*)&hT[c * 128 + (((ks * 4 + g4) ^ (cc >> 1)) << 3)];
    }

    #pragma unroll
    for (int mt = 0; mt < 4; ++mt) {
        const int kr = mt * 16 + cc;
        f32x4v aR[2], aI[2];
        aR[0] = aR[1] = aI[0] = aI[1] = (f32x4v){0.f, 0.f, 0.f, 0.f};
        #pragma unroll
        for (int ks = 0; ks < 4; ++ks) {
            const int e0 = kr * 128 + ks * 32 + g4 * 8;
            const bf16x8 A0 = *(const bf16x8*)&imgF[e0];
            const bf16x8 A1 = *(const bf16x8*)&imgF[8192 + e0];
            #pragma unroll
            for (int ct = 0; ct < 2; ++ct) {
                aR[ct] = __builtin_amdgcn_mfma_f32_16x16x32_bf16(A0, Bf[ct][ks], aR[ct], 0, 0, 0);
                aI[ct] = __builtin_amdgcn_mfma_f32_16x16x32_bf16(A1, Bf[ct][ks], aI[ct], 0, 0, 0);
            }
        }
        // energy partials (f32, before bf16 rounding)
        #pragma unroll
        for (int reg = 0; reg < 4; ++reg) {
            float e = aR[0][reg] * aR[0][reg] + aI[0][reg] * aI[0][reg]
                    + aR[1][reg] * aR[1][reg] + aI[1][reg] * aI[1][reg];
            e += __shfl_xor(e, 1, 64); e += __shfl_xor(e, 2, 64);
            e += __shfl_xor(e, 4, 64); e += __shfl_xor(e, 8, 64);
            if (cc == 0) epart[mt * 16 + g4 * 4 + reg][wv] = e;
        }
        // X store: acc (k=mt*16+g4*4+reg, c) -> Xg[b][c][plane][k] packed bf16
        #pragma unroll
        for (int ct = 0; ct < 2; ++ct) {
            const int c = wv * 32 + ct * 16 + cc;
            unsigned short* Xb = Xg + (size_t)b * XSTR + (size_t)c * 128;
            const int k0 = mt * 16 + g4 * 4;
            uint2 pr, pi;
            pr.x = cvtpk(aR[ct][0], aR[ct][1]); pr.y = cvtpk(aR[ct][2], aR[ct][3]);
            pi.x = cvtpk(aI[ct][0], aI[ct][1]); pi.y = cvtpk(aI[ct][2], aI[ct][3]);
            *(uint2*)&Xb[k0]      = pr;   // plane 0 (Re)
            *(uint2*)&Xb[64 + k0] = pi;   // plane 1 (Im)
        }
    }
    __syncthreads();
    if (t < 64) energy_s[t] = epart[t][0] + epart[t][1] + epart[t][2] + epart[t][3];
    __syncthreads();
    if (t < NF) {
        const float e = energy_s[t];
        int cnt = 0;
        for (int j = 0; j < NF; ++j) {
            const float ej = energy_s[j];
            cnt += (ej < e || (ej == e && j < t)) ? 1 : 0;
        }
        if (cnt == (NF - 1) / 2) med_s = e;
    }
    __syncthreads();
    if (t < NF) normE[b * NF + t] = energy_s[t] / (med_s + 1e-6f);
}

// ----------------------- radix round 0: LDS-aggregated histogram ----------
__global__ void k_hist0(const float* __restrict__ normE,
                        unsigned* __restrict__ hist)
{
    __shared__ unsigned lh[2048];
    for (int i = threadIdx.x; i < 2048; i += 256) lh[i] = 0;
    __syncthreads();
    for (int i = blockIdx.x * 256 + threadIdx.x; i < MTOT; i += gridDim.x * 256)
        atomicAdd(&lh[__float_as_uint(normE[i]) >> 21], 1u);
    __syncthreads();
    for (int i = threadIdx.x; i < 2048; i += 256) {
        const unsigned c = lh[i];
        if (c) atomicAdd(&hist[i], c);
    }
}

// --------------------------- radix select rounds 1 & 2 (fused hist+scan) ---
// hist layout (u32): [0,2048) round0 | [2048,6144) round1 (2 ranks) |
//                    [6144,8192) round2 (2 ranks). done: slot per (layer,phase).
__global__ void k_sel(const float* __restrict__ normE,
                      unsigned* __restrict__ hist,
                      unsigned* __restrict__ sel,
                      unsigned* __restrict__ done,
                      const float* __restrict__ thrp,
                      const int layer, const int phase,
                      float* __restrict__ thresh)
{
    __shared__ unsigned lh[4096];
    __shared__ unsigned sp[2], sc[2];
    __shared__ unsigned ticket_s;
    __shared__ float vb[2];
    const int t = threadIdx.x;
    const float q = thrp[layer] * (float)(MTOT - 1);
    const unsigned r0 = (unsigned)floorf(q);

    if (phase == 1) {
        // entry scan of round-0 hist (2048 bins, shift 21, prefix 0)
        if (t < 128) {
            const int j = t >> 6, ln = t & 63;
            const unsigned rk = r0 + (unsigned)j;
            unsigned sum = 0;
            for (int i = 0; i < 32; ++i) sum += hist[ln * 32 + i];
            unsigned pre = sum;
            #pragma unroll
            for (int off = 1; off < 64; off <<= 1) {
                const unsigned tt = __shfl_up(pre, off, 64);
                if (ln >= off) pre += tt;
            }
            const unsigned excl = pre - sum;
            if (rk >= excl && rk < excl + sum) {
                unsigned cum = excl;
                for (int i = 0; i < 32; ++i) {
                    const unsigned hc = hist[ln * 32 + i];
                    if (rk < cum + hc) { sp[j] = (unsigned)(ln * 32 + i) << 21; sc[j] = cum; break; }
                    cum += hc;
                }
            }
        }
    } else {
        if (t < 2) { sp[t] = sel[2 * t]; sc[t] = sel[2 * t + 1]; }
    }
    __syncthreads();
    const unsigned p0 = sp[0], p1 = sp[1];
    const int bins      = (phase == 1) ? 2048 : 1024;
    const int shift     = (phase == 1) ? 10 : 0;
    const unsigned hmsk = (phase == 1) ? 0xFFE00000u : 0xFFFFFC00u;
    const int region    = (phase == 1) ? 2048 : 6144;

    for (int i = t; i < 2 * bins; i += 256) lh[i] = 0;
    __syncthreads();
    for (int i = blockIdx.x * 256 + t; i < MTOT; i += gridDim.x * 256) {
        const unsigned v = __float_as_uint(normE[i]);
        const unsigned bin = (v >> shift) & (unsigned)(bins - 1);
        if ((v & hmsk) == p0) atomicAdd(&lh[bin], 1u);
        if ((v & hmsk) == p1) atomicAdd(&lh[bins + bin], 1u);
    }
    __syncthreads();
    for (int i = t; i < 2 * bins; i += 256) {
        const unsigned c = lh[i];
        if (c) atomicAdd(&hist[region + i], c);
    }
    __threadfence();
    if (t == 0) ticket_s = atomicAdd(&done[(layer << 1) + (phase - 1)], 1u);
    __syncthreads();
    if (ticket_s != (unsigned)(gridDim.x - 1)) return;
    __threadfence();

    // last block: scan both ranks of this round
    if (t < 128) {
        const int j = t >> 6, ln = t & 63;
        const unsigned rk  = r0 + (unsigned)j;
        const unsigned rem = rk - sc[j];
        const unsigned* H  = hist + region + j * bins;
        const int per = bins / 64;
        unsigned sum = 0;
        for (int i = 0; i < per; ++i)
            sum += __hip_atomic_load(&H[ln * per + i], __ATOMIC_RELAXED, __HIP_MEMORY_SCOPE_AGENT);
        unsigned pre = sum;
        #pragma unroll
        for (int off = 1; off < 64; off <<= 1) {
            const unsigned tt = __shfl_up(pre, off, 64);
            if (ln >= off) pre += tt;
        }
        const unsigned excl = pre - sum;
        if (rem >= excl && rem < excl + sum) {
            unsigned cum = excl;
            for (int i = 0; i < per; ++i) {
                const unsigned hc = __hip_atomic_load(&H[ln * per + i],
                                        __ATOMIC_RELAXED, __HIP_MEMORY_SCOPE_AGENT);
                if (rem < cum + hc) {
                    const unsigned bin = (unsigned)(ln * per + i);
                    if (phase == 1) { sel[2 * j] = sp[j] | (bin << 10); sel[2 * j + 1] = sc[j] + cum; }
                    else            vb[j] = __uint_as_float(sp[j] | bin);
                    break;
                }
                cum += hc;
            }
        }
    }
    __syncthreads();
    if (phase == 1) { for (int i = t; i < 6144; i += 256) hist[i] = 0u; }
    else            { for (int i = t; i < 2048; i += 256) hist[6144 + i] = 0u; }
    if (t == 0 && phase == 2) {
        const float frac = q - floorf(q);
        thresh[0] = vb[0] * (1.f - frac) + vb[1] * frac;
    }
}

// ===== C-fused: irfft+residual (layer l) THEN LN+fwd DFT (layer l+1) =======
// Spill-fix vs R13: the retained out-tile lives in LDS (hT), not registers.
// Phase 2 writes RAW bf16 out-values to the swizzled hT addresses; phase 4
// is a per-thread LDS RMW applying LN in place (no cross-thread dep).
__global__ __launch_bounds__(256, 4) void k_asb_fwd(
    const float* __restrict__ x,
    const float* __restrict__ cw, const float* __restrict__ cwh,
    const unsigned short* __restrict__ imgI,
    const unsigned short* __restrict__ imgF,
    const float* __restrict__ gamma_n, const float* __restrict__ beta_n,
    float* __restrict__ normE,          // read (layer l mask) AND written (layer l+1)
    const float* __restrict__ thresh,
    float* __restrict__ out,
    unsigned short* __restrict__ Xg)
{
    __shared__ __align__(16) unsigned short hT[128 * 128];   // 32 KB
    __shared__ float mask_s[64];
    __shared__ float part_s[112][4], part_q[112][4];
    __shared__ float2 musv[112];

    const int b = blockIdx.x, t = threadIdx.x;
    const int lane = t & 63, wv = t >> 6, g4 = lane >> 4, cc = lane & 15;

    if (t < 64) mask_s[t] = (t < NF && normE[b * NF + t] < thresh[0]) ? 1.f : 0.f;
    // zero-fill hT rows n in [112,128) (chunks 14,15) while hT is free
    {
        const int cf = t >> 1, chf = 14 + (t & 1);
        *(int4*)&hT[cf * 128 + ((chf ^ ((cf >> 1) & 7)) << 3)] = (int4){0, 0, 0, 0};
    }
    __syncthreads();

    // ---- phase 1: load X, weight, build inverse B-frags ----
    bf16x8 Yr[2][2], Yi[2][2];
    float gn[2], bn[2];
    #pragma unroll
    for (int ct = 0; ct < 2; ++ct) {
        const int c = wv * 32 + ct * 16 + cc;
        gn[ct] = gamma_n[c]; bn[ct] = beta_n[c];
        const unsigned short* Xb = Xg + (size_t)b * XSTR + (size_t)c * 128;
        const float2 w2 = *(const float2*)&cw[2 * c];
        const float2 h2 = *(const float2*)&cwh[2 * c];
        #pragma unroll
        for (int kb = 0; kb < 2; ++kb) {
            const bf16x8 xr = *(const bf16x8*)&Xb[kb * 32 + g4 * 8];
            const bf16x8 xi = *(const bf16x8*)&Xb[64 + kb * 32 + g4 * 8];
            float yr[8], yi[8];
            #pragma unroll
            for (int j = 0; j < 8; ++j) {
                const float m   = mask_s[kb * 32 + g4 * 8 + j];
                const float fre = fmaf(m, h2.x, w2.x);
                const float fim = fmaf(m, h2.y, w2.y);
                const float fxr = bf2f((unsigned short)xr[j]);
                const float fxi = bf2f((unsigned short)xi[j]);
                yr[j] = fxr * fre - fxi * fim;
                yi[j] = fxr * fim + fxi * fre;
            }
            unsigned ur[4], ui[4];
            #pragma unroll
            for (int jj = 0; jj < 4; ++jj) {
                ur[jj] = cvtpk(yr[2 * jj], yr[2 * jj + 1]);
                ui[jj] = cvtpk(yi[2 * jj], yi[2 * jj + 1]);
            }
            Yr[ct][kb] = *(bf16x8*)ur;
            Yi[ct][kb] = *(bf16x8*)ui;
        }
    }

    // ---- phase 2: inverse DFT + residual + store; RAW bf16 out -> hT;
    //              LN partial sums computed inline from f32 values ----
    #pragma unroll
    for (int mt = 0; mt < 7; ++mt) {
        const int nr = mt * 16 + cc;
        f32x4v o[2];
        o[0] = o[1] = (f32x4v){0.f, 0.f, 0.f, 0.f};
        #pragma unroll
        for (int kb = 0; kb < 2; ++kb) {
            const int e0 = nr * 64 + kb * 32 + g4 * 8;
            const bf16x8 A0 = *(const bf16x8*)&imgI[e0];
            const bf16x8 A1 = *(const bf16x8*)&imgI[8192 + e0];
            #pragma unroll
            for (int ct = 0; ct < 2; ++ct) {
                o[ct] = __builtin_amdgcn_mfma_f32_16x16x32_bf16(A0, Yr[ct][kb], o[ct], 0, 0, 0);
                o[ct] = __builtin_amdgcn_mfma_f32_16x16x32_bf16(A1, Yi[ct][kb], o[ct], 0, 0, 0);
            }
        }
        float vals[2][4];
        #pragma unroll
        for (int ct = 0; ct < 2; ++ct) {
            const int c = wv * 32 + ct * 16 + cc;
            #pragma unroll
            for (int reg = 0; reg < 4; ++reg) {
                const int n = mt * 16 + g4 * 4 + reg;
                float val = 0.f;
                if (n < SEQ) {
                    const size_t idx = (size_t)n * BD + (size_t)b * DIM + c;
                    val = x[idx] + o[ct][reg];
                    out[idx] = val;
                }
                vals[ct][reg] = val;
            }
            // stage raw bf16 out-values into hT (LN applied in phase 4)
            #pragma unroll
            for (int pr = 0; pr < 2; ++pr) {
                const int n0 = mt * 16 + g4 * 4 + pr * 2;
                const int e = c * 128 + (((n0 >> 3) ^ ((c >> 1) & 7)) << 3) + (n0 & 7);
                *(unsigned*)&hT[e] = cvtpk(vals[ct][pr * 2], vals[ct][pr * 2 + 1]);
            }
        }
        // LN partials for this mt's 4 rows (sum over the 2 ct + 16 cc lanes)
        #pragma unroll
        for (int reg = 0; reg < 4; ++reg) {
            float s  = vals[0][reg] + vals[1][reg];
            float s2 = fmaf(vals[0][reg], vals[0][reg], vals[1][reg] * vals[1][reg]);
            s  += __shfl_xor(s, 1, 64);  s  += __shfl_xor(s, 2, 64);
            s  += __shfl_xor(s, 4, 64);  s  += __shfl_xor(s, 8, 64);
            s2 += __shfl_xor(s2, 1, 64); s2 += __shfl_xor(s2, 2, 64);
            s2 += __shfl_xor(s2, 4, 64); s2 += __shfl_xor(s2, 8, 64);
            if (cc == 0) {
                const int n = mt * 16 + g4 * 4 + reg;
                part_s[n][wv] = s; part_q[n][wv] = s2;
            }
        }
    }
    __syncthreads();
    if (t < 112) {
        const float s  = part_s[t][0] + part_s[t][1] + part_s[t][2] + part_s[t][3];
        const float sq = part_q[t][0] + part_q[t][1] + part_q[t][2] + part_q[t][3];
        const float mu = s * (1.f / 128.f);
        const float rstd = rsqrtf(sq * (1.f / 128.f) - mu * mu + 1e-5f);
        musv[t] = make_float2(mu, rstd);
    }
    __syncthreads();

    // ---- phase 4: in-place LN on hT (per-thread RMW of own addresses) ----
    #pragma unroll
    for (int mt = 0; mt < 7; ++mt) {
        #pragma unroll
        for (int ct = 0; ct < 2; ++ct) {
            const int c = wv * 32 + ct * 16 + cc;
            #pragma unroll
            for (int pr = 0; pr < 2; ++pr) {
                const int n0 = mt * 16 + g4 * 4 + pr * 2;
                const int e = c * 128 + (((n0 >> 3) ^ ((c >> 1) & 7)) << 3) + (n0 & 7);
                const unsigned pv = *(const unsigned*)&hT[e];
                float h0 = 0.f, h1 = 0.f;
                if (n0 < SEQ) {
                    const float2 ms = musv[n0];
                    const float v0 = bf2f((unsigned short)(pv & 0xFFFFu));
                    h0 = fmaf((v0 - ms.x) * ms.y, gn[ct], bn[ct]);
                }
                if (n0 + 1 < SEQ) {
                    const float2 ms = musv[n0 + 1];
                    const float v1 = bf2f((unsigned short)(pv >> 16));
                    h1 = fmaf((v1 - ms.x) * ms.y, gn[ct], bn[ct]);
                }
                *(unsigned*)&hT[e] = cvtpk(h0, h1);
            }
        }
    }
    __syncthreads();

    // ---- phase 5: fwd DFT + energy + median + normE (hT-union tail) ----
    {
        bf16x8 Bf[2][4];
        #pragma unroll
        for (int ct = 0; ct < 2; ++ct) {
            const int c = wv * 32 + ct * 16 + cc;
            #pragma unroll
            for (int ks = 0; ks < 4; ++ks)
                Bf[ct][ks] = *(const bf16x8*)&hT[c * 128 + (((ks * 4 + g4) ^ (cc >> 1)) << 3)];
        }
        __syncthreads();   // hT dead -> reuse front as f32 scratch

        float* epart    = (float*)hT;          // [64][4]
        float* energy_s = (float*)hT + 256;    // [64]
        float* medp     = (float*)hT + 320;    // [1]

        #pragma unroll
        for (int mt = 0; mt < 4; ++mt) {
            const int kr = mt * 16 + cc;
            f32x4v aR[2], aI[2];
            aR[0] = aR[1] = aI[0] = aI[1] = (f32x4v){0.f, 0.f, 0.f, 0.f};
            #pragma unroll
            for (int ks = 0; ks < 4; ++ks) {
                const int e0 = kr * 128 + ks * 32 + g4 * 8;
                const bf16x8 A0 = *(const bf16x8*)&imgF[e0];
                const bf16x8 A1 = *(const bf16x8*)&imgF[8192 + e0];
                #pragma unroll
                for (int ct = 0; ct < 2; ++ct) {
                    aR[ct] = __builtin_amdgcn_mfma_f32_16x16x32_bf16(A0, Bf[ct][ks], aR[ct], 0, 0, 0);
                    aI[ct] = __builtin_amdgcn_mfma_f32_16x16x32_bf16(A1, Bf[ct][ks], aI[ct], 0, 0, 0);
                }
            }
            #pragma unroll
            for (int reg = 0; reg < 4; ++reg) {
                float e = aR[0][reg] * aR[0][reg] + aI[0][reg] * aI[0][reg]
                        + aR[1][reg] * aR[1][reg] + aI[1][reg] * aI[1][reg];
                e += __shfl_xor(e, 1, 64); e += __shfl_xor(e, 2, 64);
                e += __shfl_xor(e, 4, 64); e += __shfl_xor(e, 8, 64);
                if (cc == 0) epart[(mt * 16 + g4 * 4 + reg) * 4 + wv] = e;
            }
            #pragma unroll
            for (int ct = 0; ct < 2; ++ct) {
                const int c = wv * 32 + ct * 16 + cc;
                unsigned short* Xb = Xg + (size_t)b * XSTR + (size_t)c * 128;
                const int k0 = mt * 16 + g4 * 4;
                uint2 pr, pi;
                pr.x = cvtpk(aR[ct][0], aR[ct][1]); pr.y = cvtpk(aR[ct][2], aR[ct][3]);
                pi.x = cvtpk(aI[ct][0], aI[ct][1]); pi.y = cvtpk(aI[ct][2], aI[ct][3]);
                *(uint2*)&Xb[k0]      = pr;
                *(uint2*)&Xb[64 + k0] = pi;
            }
        }
        __syncthreads();
        if (t < 64) energy_s[t] = epart[4 * t] + epart[4 * t + 1]
                                + epart[4 * t + 2] + epart[4 * t + 3];
        __syncthreads();
        if (t < NF) {
            const float e = energy_s[t];
            int cnt = 0;
            for (int j = 0; j < NF; ++j) {
                const float ej = energy_s[j];
                cnt += (ej < e || (ej == e && j < t)) ? 1 : 0;
            }
            if (cnt == (NF - 1) / 2) *medp = e;
        }
        __syncthreads();
        if (t < NF) normE[b * NF + t] = energy_s[t] / (*medp + 1e-6f);
    }
}

// --------------- C-final: load X + weight + irfft + residual ---------------
__global__ __launch_bounds__(256, 4) void k_asb(
    const float* __restrict__ x,
    const float* __restrict__ cw, const float* __restrict__ cwh,
    const unsigned short* __restrict__ Xg,
    const unsigned short* __restrict__ imgI,
    const float* __restrict__ normE, const float* __restrict__ thresh,
    float* __restrict__ out)
{
    __shared__ __align__(16) float mask_s[64];

    const int b = blockIdx.x, t = threadIdx.x;
    const int lane = t & 63, wv = t >> 6, g4 = lane >> 4, cc = lane & 15;

    if (t < 64) mask_s[t] = (t < NF && normE[b * NF + t] < thresh[0]) ? 1.f : 0.f;
    __syncthreads();

    bf16x8 Yr[2][2], Yi[2][2];
    #pragma unroll
    for (int ct = 0; ct < 2; ++ct) {
        const int c = wv * 32 + ct * 16 + cc;
        const unsigned short* Xb = Xg + (size_t)b * XSTR + (size_t)c * 128;
        const float2 w2 = *(const float2*)&cw[2 * c];
        const float2 h2 = *(const float2*)&cwh[2 * c];
        #pragma unroll
        for (int kb = 0; kb < 2; ++kb) {
            const bf16x8 xr = *(const bf16x8*)&Xb[kb * 32 + g4 * 8];
            const bf16x8 xi = *(const bf16x8*)&Xb[64 + kb * 32 + g4 * 8];
            float yr[8], yi[8];
            #pragma unroll
            for (int j = 0; j < 8; ++j) {
                const float m   = mask_s[kb * 32 + g4 * 8 + j];
                const float fre = fmaf(m, h2.x, w2.x);
                const float fim = fmaf(m, h2.y, w2.y);
                const float fxr = bf2f((unsigned short)xr[j]);
                const float fxi = bf2f((unsigned short)xi[j]);
                yr[j] = fxr * fre - fxi * fim;
                yi[j] = fxr * fim + fxi * fre;
            }
            unsigned ur[4], ui[4];
            #pragma unroll
            for (int jj = 0; jj < 4; ++jj) {
                ur[jj] = cvtpk(yr[2 * jj], yr[2 * jj + 1]);
                ui[jj] = cvtpk(yi[2 * jj], yi[2 * jj + 1]);
            }
            Yr[ct][kb] = *(bf16x8*)ur;
            Yi[ct][kb] = *(bf16x8*)ui;
        }
    }

    #pragma unroll
    for (int mt = 0; mt < 7; ++mt) {
        const int nr = mt * 16 + cc;
        f32x4v o[2];
        o[0] = o[1] = (f32x4v){0.f, 0.f, 0.f, 0.f};
        #pragma unroll
        for (int kb = 0; kb < 2; ++kb) {
            const int e0 = nr * 64 + kb * 32 + g4 * 8;
            const bf16x8 A0 = *(const bf16x8*)&imgI[e0];
            const bf16x8 A1 = *(const bf16x8*)&imgI[8192 + e0];
            #pragma unroll
            for (int ct = 0; ct < 2; ++ct) {
                o[ct] = __builtin_amdgcn_mfma_f32_16x16x32_bf16(A0, Yr[ct][kb], o[ct], 0, 0, 0);
                o[ct] = __builtin_amdgcn_mfma_f32_16x16x32_bf16(A1, Yi[ct][kb], o[ct], 0, 0, 0);
            }
        }
        #pragma unroll
        for (int ct = 0; ct < 2; ++ct) {
            const int c = wv * 32 + ct * 16 + cc;
            #pragma unroll
            for (int reg = 0; reg < 4; ++reg) {
                const int n = mt * 16 + g4 * 4 + reg;
                if (n < SEQ) {
                    const size_t idx = (size_t)n * BD + (size_t)b * DIM + c;
                    out[idx] = x[idx] + o[ct][reg];
                }
            }
        }
    }
}

// ---------------------------------------------------------------------------
extern "C" void kernel_launch(void* const* d_in, const int* in_sizes, int n_in,
                              void* d_out, int out_size, void* d_ws, size_t ws_size,
                              hipStream_t stream)
{
    (void)in_sizes; (void)n_in; (void)out_size; (void)ws_size;
    const float* x    = (const float*)d_in[0];
    const float* cw   = (const float*)d_in[1];
    const float* cwh  = (const float*)d_in[2];
    const float* thrp = (const float*)d_in[3];
    const float* gam  = (const float*)d_in[4];
    const float* bet  = (const float*)d_in[5];
    float* out = (float*)d_out;

    char* ws = (char*)d_ws;
    unsigned short* imgF = (unsigned short*)(ws);                    // 32768 B
    unsigned short* imgI = (unsigned short*)(ws + 32768);            // 32768 B
    unsigned short* Xg   = (unsigned short*)(ws + 65536);            // 67,108,864 B
    float* normE    = (float*)(ws + 65536 + 67108864);               // 417,792 B
    unsigned* hist  = (unsigned*)(ws + 65536 + 67108864 + 417792);   // 32768 B
    unsigned* done  = (unsigned*)(ws + 65536 + 67108864 + 417792 + 32768);       // 64 B
    unsigned* sel   = (unsigned*)(ws + 65536 + 67108864 + 417792 + 32768 + 64);  // 64 B
    float* thresh   = (float*)(ws + 65536 + 67108864 + 417792 + 32768 + 128);

    k_tables<<<64, 256, 0, stream>>>(imgF, imgI);
    (void)hipMemsetAsync(hist, 0, 32768 + 64, stream);   // hist + done (4 slots)

    // layer 0 fwd
    k_fwd<<<BATCH, 256, 0, stream>>>(x, gam, bet, imgF, Xg, normE);
    k_hist0<<<96, 256, 0, stream>>>(normE, hist);
    k_sel<<<96, 256, 0, stream>>>(normE, hist, sel, done, thrp, 0, 1, thresh);
    k_sel<<<96, 256, 0, stream>>>(normE, hist, sel, done, thrp, 0, 2, thresh);
    // layer 0 asb + layer 1 fwd (fused, LDS-retained tile)
    k_asb_fwd<<<BATCH, 256, 0, stream>>>(x, cw, cwh, imgI, imgF,
                                         gam + DIM, bet + DIM,
                                         normE, thresh, out, Xg);
    k_hist0<<<96, 256, 0, stream>>>(normE, hist);
    k_sel<<<96, 256, 0, stream>>>(normE, hist, sel, done, thrp, 1, 1, thresh);
    k_sel<<<96, 256, 0, stream>>>(normE, hist, sel, done, thrp, 1, 2, thresh);
    // layer 1 asb (final)
    k_asb<<<BATCH, 256, 0, stream>>>(out, cw + DIM * 2, cwh + DIM * 2,
                                     Xg, imgI, normE, thresh, out);
}